// Round 2
// baseline (5340.122 us; speedup 1.0000x reference)
//
#include <hip/hip_runtime.h>
#include <hip/hip_bf16.h>

// Problem: CausalSelfAttention  B=2, T=2048, C=1024, H=16, D=64
// Inputs (fp32 per reference): x[B,T,C], W_attn[C,3C], b_attn[3C],
//   W_proj[C,C], b_proj[C].  Output fp32 y[B,T,C].
// Round 1: correctness-first fp32 pipeline (no MFMA yet). Threshold is
// bf16-lenient (0.103) so bf16 MFMA is available for later rounds.

#define B_  2
#define T_  2048
#define C_  1024
#define H_  16
#define D_  64
#define M_  (B_ * T_)      // 4096 rows
#define N3_ (3 * C_)       // 3072

// ---------------------------------------------------------------------------
// Kernel 1: qkv = x @ W_attn + b_attn, scattered to Q/K/V in [B,H,T,D] fp32.
// 64x64 output tile per 256-thread block, K-step 16, 4x4 micro-tile/thread.
// ---------------------------------------------------------------------------
__global__ __launch_bounds__(256) void qkv_gemm(
    const float* __restrict__ x,
    const float* __restrict__ W,
    const float* __restrict__ bias,
    float* __restrict__ Q, float* __restrict__ Kd, float* __restrict__ V)
{
    __shared__ float As[64][17];   // +1 pad: breaks bank conflicts
    __shared__ float Bs[16][65];

    const int tid = threadIdx.x;
    const int tx  = tid & 15;      // 0..15 -> 4 output cols each
    const int ty  = tid >> 4;      // 0..15 -> 4 output rows each
    const int n0  = blockIdx.x * 64;
    const int m0  = blockIdx.y * 64;

    float acc[4][4] = {};

    for (int k0 = 0; k0 < C_; k0 += 16) {
        {   // A tile 64x16: 1024 floats = 256 float4, one per thread
            int r = tid >> 2, c = (tid & 3) * 4;
            float4 a4 = *(const float4*)&x[(size_t)(m0 + r) * C_ + k0 + c];
            As[r][c + 0] = a4.x; As[r][c + 1] = a4.y;
            As[r][c + 2] = a4.z; As[r][c + 3] = a4.w;
        }
        {   // B tile 16x64
            int r = tid >> 4, c = (tid & 15) * 4;
            float4 b4 = *(const float4*)&W[(size_t)(k0 + r) * N3_ + n0 + c];
            Bs[r][c + 0] = b4.x; Bs[r][c + 1] = b4.y;
            Bs[r][c + 2] = b4.z; Bs[r][c + 3] = b4.w;
        }
        __syncthreads();
        #pragma unroll
        for (int k = 0; k < 16; k++) {
            float a[4], b[4];
            #pragma unroll
            for (int i = 0; i < 4; i++) a[i] = As[ty * 4 + i][k];
            #pragma unroll
            for (int j = 0; j < 4; j++) b[j] = Bs[k][tx * 4 + j];
            #pragma unroll
            for (int i = 0; i < 4; i++)
                #pragma unroll
                for (int j = 0; j < 4; j++) acc[i][j] += a[i] * b[j];
        }
        __syncthreads();
    }

    #pragma unroll
    for (int i = 0; i < 4; i++) {
        int m  = m0 + ty * 4 + i;
        int bb = m >> 11;          // / T_
        int t  = m & (T_ - 1);
        #pragma unroll
        for (int j = 0; j < 4; j++) {
            int n = n0 + tx * 4 + j;
            float v = acc[i][j] + bias[n];
            int which = n >> 10;   // 0=Q 1=K 2=V
            int c = n & (C_ - 1);
            int h = c >> 6;        // / D_
            int d = c & (D_ - 1);
            float* dst = (which == 0) ? Q : (which == 1) ? Kd : V;
            dst[(((size_t)bb * H_ + h) * T_ + t) * D_ + d] = v;
        }
    }
}

// ---------------------------------------------------------------------------
// Kernel 2: causal attention, one 64-lane wave per (b,h,q) row.
// Lane d owns dim d of Q-row and output. Online softmax over keys j<=q.
// NOTE faithful scale: att = (q.k) * sqrt(D) = dot * 8.0
// ---------------------------------------------------------------------------
__global__ __launch_bounds__(64) void attn(
    const float* __restrict__ Q, const float* __restrict__ K,
    const float* __restrict__ V, float* __restrict__ Y)
{
    const int gid = blockIdx.x;            // [0, B*H*T)
    const int q   = gid & (T_ - 1);
    const int bh  = gid >> 11;             // /T_
    const int d   = threadIdx.x;

    const size_t base = (size_t)bh * T_ * D_;
    const float* Kp = K + base;
    const float* Vp = V + base;
    const float  qv = Q[base + (size_t)q * D_ + d];

    float m = -INFINITY, l = 0.f, acc = 0.f;
    for (int j = 0; j <= q; j++) {
        float s = qv * Kp[(size_t)j * D_ + d];
        #pragma unroll
        for (int off = 32; off; off >>= 1) s += __shfl_xor(s, off, 64);
        s *= 8.0f;                         // sqrt(HEAD_DIM), faithful to ref
        float mn = fmaxf(m, s);
        float c0 = __expf(m - mn);         // 0 when m = -inf
        float p  = __expf(s - mn);
        l   = l * c0 + p;
        acc = acc * c0 + p * Vp[(size_t)j * D_ + d];
        m = mn;
    }

    const int b = bh >> 4, h = bh & (H_ - 1);
    Y[((size_t)b * T_ + q) * C_ + h * D_ + d] = acc / l;
}

// ---------------------------------------------------------------------------
// Kernel 3: out = Yatt @ W_proj + b_proj  (all fp32)
// ---------------------------------------------------------------------------
__global__ __launch_bounds__(256) void proj_gemm(
    const float* __restrict__ A,
    const float* __restrict__ W,
    const float* __restrict__ bias,
    float* __restrict__ out)
{
    __shared__ float As[64][17];
    __shared__ float Bs[16][65];

    const int tid = threadIdx.x;
    const int tx  = tid & 15;
    const int ty  = tid >> 4;
    const int n0  = blockIdx.x * 64;
    const int m0  = blockIdx.y * 64;

    float acc[4][4] = {};

    for (int k0 = 0; k0 < C_; k0 += 16) {
        {
            int r = tid >> 2, c = (tid & 3) * 4;
            float4 a4 = *(const float4*)&A[(size_t)(m0 + r) * C_ + k0 + c];
            As[r][c + 0] = a4.x; As[r][c + 1] = a4.y;
            As[r][c + 2] = a4.z; As[r][c + 3] = a4.w;
        }
        {
            int r = tid >> 4, c = (tid & 15) * 4;
            float4 b4 = *(const float4*)&W[(size_t)(k0 + r) * C_ + n0 + c];
            Bs[r][c + 0] = b4.x; Bs[r][c + 1] = b4.y;
            Bs[r][c + 2] = b4.z; Bs[r][c + 3] = b4.w;
        }
        __syncthreads();
        #pragma unroll
        for (int k = 0; k < 16; k++) {
            float a[4], b[4];
            #pragma unroll
            for (int i = 0; i < 4; i++) a[i] = As[ty * 4 + i][k];
            #pragma unroll
            for (int j = 0; j < 4; j++) b[j] = Bs[k][tx * 4 + j];
            #pragma unroll
            for (int i = 0; i < 4; i++)
                #pragma unroll
                for (int j = 0; j < 4; j++) acc[i][j] += a[i] * b[j];
        }
        __syncthreads();
    }

    #pragma unroll
    for (int i = 0; i < 4; i++) {
        int m = m0 + ty * 4 + i;
        #pragma unroll
        for (int j = 0; j < 4; j++) {
            int n = n0 + tx * 4 + j;
            out[(size_t)m * C_ + n] = acc[i][j] + bias[n];
        }
    }
}

// ---------------------------------------------------------------------------
extern "C" void kernel_launch(void* const* d_in, const int* in_sizes, int n_in,
                              void* d_out, int out_size, void* d_ws, size_t ws_size,
                              hipStream_t stream)
{
    const float* x      = (const float*)d_in[0];
    const float* W_attn = (const float*)d_in[1];
    const float* b_attn = (const float*)d_in[2];
    const float* W_proj = (const float*)d_in[3];
    const float* b_proj = (const float*)d_in[4];
    float* out = (float*)d_out;

    // ws layout (fp32): Q | K | V  each [B,H,T,D], then Yatt [B,T,C]  (64 MB)
    const size_t per = (size_t)B_ * H_ * T_ * D_;   // 4M floats
    float* ws = (float*)d_ws;
    float* Q  = ws;
    float* K  = Q + per;
    float* V  = K + per;
    float* Y  = V + per;

    qkv_gemm<<<dim3(N3_ / 64, M_ / 64), 256, 0, stream>>>(x, W_attn, b_attn, Q, K, V);
    attn<<<dim3(B_ * H_ * T_), 64, 0, stream>>>(Q, K, V, Y);
    proj_gemm<<<dim3(C_ / 64, M_ / 64), 256, 0, stream>>>(Y, W_proj, b_proj, out);
}

// Round 3
// 1054.729 us; speedup vs baseline: 5.0630x; 5.0630x over previous
//
#include <hip/hip_runtime.h>
#include <hip/hip_bf16.h>

// Problem: CausalSelfAttention  B=2, T=2048, C=1024, H=16, D=64
// Inputs (fp32): x[B,T,C], W_attn[C,3C], b_attn[3C], W_proj[C,C], b_proj[C].
// Output fp32 y[B,T,C].  Threshold is bf16-lenient (0.103).
// Round 3: flash-style tiled attention (fp32 VALU), balanced causal pairing.

#define B_  2
#define T_  2048
#define C_  1024
#define H_  16
#define D_  64
#define M_  (B_ * T_)      // 4096 rows
#define N3_ (3 * C_)       // 3072

// ---------------------------------------------------------------------------
// Kernel 1: qkv = x @ W_attn + b_attn, scattered to Q/K/V in [B,H,T,D] fp32.
// ---------------------------------------------------------------------------
__global__ __launch_bounds__(256) void qkv_gemm(
    const float* __restrict__ x,
    const float* __restrict__ W,
    const float* __restrict__ bias,
    float* __restrict__ Q, float* __restrict__ Kd, float* __restrict__ V)
{
    __shared__ float As[64][17];
    __shared__ float Bs[16][65];

    const int tid = threadIdx.x;
    const int tx  = tid & 15;
    const int ty  = tid >> 4;
    const int n0  = blockIdx.x * 64;
    const int m0  = blockIdx.y * 64;

    float acc[4][4] = {};

    for (int k0 = 0; k0 < C_; k0 += 16) {
        {
            int r = tid >> 2, c = (tid & 3) * 4;
            float4 a4 = *(const float4*)&x[(size_t)(m0 + r) * C_ + k0 + c];
            As[r][c + 0] = a4.x; As[r][c + 1] = a4.y;
            As[r][c + 2] = a4.z; As[r][c + 3] = a4.w;
        }
        {
            int r = tid >> 4, c = (tid & 15) * 4;
            float4 b4 = *(const float4*)&W[(size_t)(k0 + r) * N3_ + n0 + c];
            Bs[r][c + 0] = b4.x; Bs[r][c + 1] = b4.y;
            Bs[r][c + 2] = b4.z; Bs[r][c + 3] = b4.w;
        }
        __syncthreads();
        #pragma unroll
        for (int k = 0; k < 16; k++) {
            float a[4], b[4];
            #pragma unroll
            for (int i = 0; i < 4; i++) a[i] = As[ty * 4 + i][k];
            #pragma unroll
            for (int j = 0; j < 4; j++) b[j] = Bs[k][tx * 4 + j];
            #pragma unroll
            for (int i = 0; i < 4; i++)
                #pragma unroll
                for (int j = 0; j < 4; j++) acc[i][j] += a[i] * b[j];
        }
        __syncthreads();
    }

    #pragma unroll
    for (int i = 0; i < 4; i++) {
        int m  = m0 + ty * 4 + i;
        int bb = m >> 11;
        int t  = m & (T_ - 1);
        #pragma unroll
        for (int j = 0; j < 4; j++) {
            int n = n0 + tx * 4 + j;
            float v = acc[i][j] + bias[n];
            int which = n >> 10;
            int c = n & (C_ - 1);
            int h = c >> 6;
            int d = c & (D_ - 1);
            float* dst = (which == 0) ? Q : (which == 1) ? Kd : V;
            dst[(((size_t)bb * H_ + h) * T_ + t) * D_ + d] = v;
        }
    }
}

// ---------------------------------------------------------------------------
// Kernel 2: flash-style causal attention, fp32.
// Block = 256 threads, handles (b,h) x {q-tile qt, q-tile 31-qt} (balanced).
// 64x64 tiles; thread (ty,tx) owns 4 q-rows x 4 cols micro-tile.
// LDS stride 66: rows 8B-aligned (float2 reads), modest store conflicts.
// Faithful scale: att = (q.k) * sqrt(D) = dot * 8.0
// ---------------------------------------------------------------------------
__global__ __launch_bounds__(256) void attn_tiled(
    const float* __restrict__ Q, const float* __restrict__ K,
    const float* __restrict__ V, float* __restrict__ Y)
{
    __shared__ float QsT[64][66];   // Q^T: [d][qrow]
    __shared__ float KsT[64][66];   // K^T: [d][key];  reused as P^T: [key][qrow]
    __shared__ float Vs [64][66];   // V:   [key][d]

    const int tid = threadIdx.x;
    const int tx  = tid & 15;
    const int ty  = tid >> 4;          // 0..15
    const int tx4 = tx * 4, ty4 = ty * 4;
    const int bh  = blockIdx.y;        // 0..31
    const int b   = bh >> 4, h = bh & (H_ - 1);
    const size_t base = (size_t)bh * T_ * D_;

    for (int half = 0; half < 2; half++) {
        const int qt = (half == 0) ? blockIdx.x : 31 - blockIdx.x;
        const int q0 = qt * 64;

        __syncthreads();   // previous q-tile's readers done before QsT overwrite
        #pragma unroll
        for (int i = 0; i < 4; i++) {   // load Q tile, store transposed
            int row = i * 16 + ty;
            float4 a4 = *(const float4*)&Q[base + (size_t)(q0 + row) * D_ + tx4];
            QsT[tx4 + 0][row] = a4.x; QsT[tx4 + 1][row] = a4.y;
            QsT[tx4 + 2][row] = a4.z; QsT[tx4 + 3][row] = a4.w;
        }

        float m[4], l[4], O[4][4];
        #pragma unroll
        for (int i = 0; i < 4; i++) {
            m[i] = -INFINITY; l[i] = 0.f;
            #pragma unroll
            for (int j = 0; j < 4; j++) O[i][j] = 0.f;
        }

        for (int kt = 0; kt <= qt; kt++) {
            __syncthreads();   // prev PV readers done before K/V overwrite
            #pragma unroll
            for (int i = 0; i < 4; i++) {
                int row = i * 16 + ty;
                const float* kp = &K[base + (size_t)(kt * 64 + row) * D_ + tx4];
                const float* vp = &V[base + (size_t)(kt * 64 + row) * D_ + tx4];
                float4 k4 = *(const float4*)kp;
                KsT[tx4 + 0][row] = k4.x; KsT[tx4 + 1][row] = k4.y;
                KsT[tx4 + 2][row] = k4.z; KsT[tx4 + 3][row] = k4.w;
                *(float4*)&Vs[row][tx4] = *(const float4*)vp;
            }
            __syncthreads();

            // ---- S = Q K^T (4x4 per thread) ----
            float s[4][4] = {};
            #pragma unroll 8
            for (int k = 0; k < 64; k++) {
                float2 a01 = *(const float2*)&QsT[k][ty4];
                float2 a23 = *(const float2*)&QsT[k][ty4 + 2];
                float2 b01 = *(const float2*)&KsT[k][tx4];
                float2 b23 = *(const float2*)&KsT[k][tx4 + 2];
                float a[4] = {a01.x, a01.y, a23.x, a23.y};
                float bb[4] = {b01.x, b01.y, b23.x, b23.y};
                #pragma unroll
                for (int i = 0; i < 4; i++)
                    #pragma unroll
                    for (int j = 0; j < 4; j++) s[i][j] += a[i] * bb[j];
            }

            // scale (faithful sqrt(D)) + causal mask on the diagonal tile
            #pragma unroll
            for (int i = 0; i < 4; i++)
                #pragma unroll
                for (int j = 0; j < 4; j++) {
                    s[i][j] *= 8.0f;
                    if (kt == qt && (tx4 + j) > (ty4 + i)) s[i][j] = -INFINITY;
                }

            // ---- online softmax update ----
            float mnew[4], alpha[4], rsum[4];
            #pragma unroll
            for (int i = 0; i < 4; i++) {
                float rm = fmaxf(fmaxf(s[i][0], s[i][1]), fmaxf(s[i][2], s[i][3]));
                #pragma unroll
                for (int off = 1; off < 16; off <<= 1)
                    rm = fmaxf(rm, __shfl_xor(rm, off, 64));
                mnew[i]  = fmaxf(m[i], rm);
                alpha[i] = __expf(m[i] - mnew[i]);
                float rs = 0.f;
                #pragma unroll
                for (int j = 0; j < 4; j++) {
                    s[i][j] = __expf(s[i][j] - mnew[i]);   // s becomes p
                    rs += s[i][j];
                }
                #pragma unroll
                for (int off = 1; off < 16; off <<= 1)
                    rs += __shfl_xor(rs, off, 64);
                rsum[i] = rs;
            }
            #pragma unroll
            for (int i = 0; i < 4; i++) {
                l[i] = l[i] * alpha[i] + rsum[i];
                m[i] = mnew[i];
                #pragma unroll
                for (int j = 0; j < 4; j++) O[i][j] *= alpha[i];
            }

            __syncthreads();   // all S-readers of KsT done before P overwrite
            #pragma unroll
            for (int i = 0; i < 4; i++)
                #pragma unroll
                for (int j = 0; j < 4; j++)
                    KsT[tx4 + j][ty4 + i] = s[i][j];   // P^T: [key][qrow]
            __syncthreads();

            // ---- O += P V (4x4 per thread) ----
            #pragma unroll 8
            for (int kk = 0; kk < 64; kk++) {
                float2 a01 = *(const float2*)&KsT[kk][ty4];
                float2 a23 = *(const float2*)&KsT[kk][ty4 + 2];
                float2 b01 = *(const float2*)&Vs[kk][tx4];
                float2 b23 = *(const float2*)&Vs[kk][tx4 + 2];
                float a[4] = {a01.x, a01.y, a23.x, a23.y};
                float bb[4] = {b01.x, b01.y, b23.x, b23.y};
                #pragma unroll
                for (int i = 0; i < 4; i++)
                    #pragma unroll
                    for (int j = 0; j < 4; j++) O[i][j] += a[i] * bb[j];
            }
        }

        // ---- epilogue: normalize, write Y[b, q0+row, h*64 + d] ----
        #pragma unroll
        for (int i = 0; i < 4; i++) {
            float inv = 1.0f / l[i];
            float4 o4;
            o4.x = O[i][0] * inv; o4.y = O[i][1] * inv;
            o4.z = O[i][2] * inv; o4.w = O[i][3] * inv;
            *(float4*)&Y[((size_t)b * T_ + (q0 + ty4 + i)) * C_ + h * D_ + tx4] = o4;
        }
    }
}

// ---------------------------------------------------------------------------
// Kernel 3: out = Yatt @ W_proj + b_proj  (all fp32)
// ---------------------------------------------------------------------------
__global__ __launch_bounds__(256) void proj_gemm(
    const float* __restrict__ A,
    const float* __restrict__ W,
    const float* __restrict__ bias,
    float* __restrict__ out)
{
    __shared__ float As[64][17];
    __shared__ float Bs[16][65];

    const int tid = threadIdx.x;
    const int tx  = tid & 15;
    const int ty  = tid >> 4;
    const int n0  = blockIdx.x * 64;
    const int m0  = blockIdx.y * 64;

    float acc[4][4] = {};

    for (int k0 = 0; k0 < C_; k0 += 16) {
        {
            int r = tid >> 2, c = (tid & 3) * 4;
            float4 a4 = *(const float4*)&A[(size_t)(m0 + r) * C_ + k0 + c];
            As[r][c + 0] = a4.x; As[r][c + 1] = a4.y;
            As[r][c + 2] = a4.z; As[r][c + 3] = a4.w;
        }
        {
            int r = tid >> 4, c = (tid & 15) * 4;
            float4 b4 = *(const float4*)&W[(size_t)(k0 + r) * C_ + n0 + c];
            Bs[r][c + 0] = b4.x; Bs[r][c + 1] = b4.y;
            Bs[r][c + 2] = b4.z; Bs[r][c + 3] = b4.w;
        }
        __syncthreads();
        #pragma unroll
        for (int k = 0; k < 16; k++) {
            float a[4], b[4];
            #pragma unroll
            for (int i = 0; i < 4; i++) a[i] = As[ty * 4 + i][k];
            #pragma unroll
            for (int j = 0; j < 4; j++) b[j] = Bs[k][tx * 4 + j];
            #pragma unroll
            for (int i = 0; i < 4; i++)
                #pragma unroll
                for (int j = 0; j < 4; j++) acc[i][j] += a[i] * b[j];
        }
        __syncthreads();
    }

    #pragma unroll
    for (int i = 0; i < 4; i++) {
        int m = m0 + ty * 4 + i;
        #pragma unroll
        for (int j = 0; j < 4; j++) {
            int n = n0 + tx * 4 + j;
            out[(size_t)m * C_ + n] = acc[i][j] + bias[n];
        }
    }
}

// ---------------------------------------------------------------------------
extern "C" void kernel_launch(void* const* d_in, const int* in_sizes, int n_in,
                              void* d_out, int out_size, void* d_ws, size_t ws_size,
                              hipStream_t stream)
{
    const float* x      = (const float*)d_in[0];
    const float* W_attn = (const float*)d_in[1];
    const float* b_attn = (const float*)d_in[2];
    const float* W_proj = (const float*)d_in[3];
    const float* b_proj = (const float*)d_in[4];
    float* out = (float*)d_out;

    const size_t per = (size_t)B_ * H_ * T_ * D_;   // 4M floats
    float* ws = (float*)d_ws;
    float* Q  = ws;
    float* K  = Q + per;
    float* V  = K + per;
    float* Y  = V + per;

    qkv_gemm<<<dim3(N3_ / 64, M_ / 64), 256, 0, stream>>>(x, W_attn, b_attn, Q, K, V);
    attn_tiled<<<dim3(16, 32), 256, 0, stream>>>(Q, K, V, Y);
    proj_gemm<<<dim3(C_ / 64, M_ / 64), 256, 0, stream>>>(Y, W_proj, b_proj, out);
}

// Round 7
// 552.622 us; speedup vs baseline: 9.6632x; 1.9086x over previous
//
#include <hip/hip_runtime.h>
#include <hip/hip_bf16.h>

// Problem: CausalSelfAttention  B=2, T=2048, C=1024, H=16, D=64
// Round 7: fix round-6 ws overlap (xh/xl were 8 MB each, clobbered WaTh).
// x hi/lo split now fused into qkv staging (reads fp32 x directly).
// ws (62 MB, no overlap): Qf 16 | Kf 16 | Vb 8 | WaTh 6 | WaTl 6 | WpT 2 | Yb 8
// Numerics: S=8*(q.k) has std~64 -> near-argmax softmax amplifies q/k rounding.
// qkv GEMM = bf16x3 split-MFMA (hh+hl+lh, ~2^-17 input precision), Q/K fp32,
// S in fp32 VALU flash attn. V / P / proj single bf16 (insensitive).

#define B_  2
#define T_  2048
#define C_  1024
#define H_  16
#define D_  64
#define M_  (B_ * T_)      // 4096
#define N3_ (3 * C_)       // 3072

typedef __attribute__((ext_vector_type(8))) short s16x8;
typedef __attribute__((ext_vector_type(4))) float f32x4;

__device__ __forceinline__ float b2f(unsigned short u) {
    return __uint_as_float(((unsigned)u) << 16);
}
__device__ __forceinline__ unsigned short f2b(float f) {   // RNE bf16 round
    unsigned u = __float_as_uint(f);
    return (unsigned short)((u + 0x7FFFu + ((u >> 16) & 1u)) >> 16);
}

// ---------------------------------------------------------------------------
// fp32 [R,Cn] -> (hi,lo) bf16 [Cn,R] transpose+split. grid (Cn/64, R/64).
// ---------------------------------------------------------------------------
__global__ __launch_bounds__(256) void cvtT_split(
    const float* __restrict__ in, short* __restrict__ oh, short* __restrict__ ol,
    int R, int Cn)
{
    __shared__ short th[64][80];
    __shared__ short tl[64][80];
    const int tid = threadIdx.x;
    const int k0 = blockIdx.y * 64;
    const int n0 = blockIdx.x * 64;
    {
        int rl = tid >> 4, cl = (tid & 15) * 4;
        #pragma unroll
        for (int i = 0; i < 4; i++) {
            int kr = rl + i * 16;
            float4 v4 = *(const float4*)&in[(size_t)(k0 + kr) * Cn + n0 + cl];
            float v[4] = {v4.x, v4.y, v4.z, v4.w};
            #pragma unroll
            for (int j = 0; j < 4; j++) {
                unsigned short hb = f2b(v[j]);
                th[cl + j][kr] = (short)hb;
                tl[cl + j][kr] = (short)f2b(v[j] - b2f(hb));
            }
        }
    }
    __syncthreads();
    {
        int ro = tid >> 2, co = (tid & 3) * 16;
        *(s16x8*)&oh[(size_t)(n0 + ro) * R + k0 + co]     = *(s16x8*)&th[ro][co];
        *(s16x8*)&oh[(size_t)(n0 + ro) * R + k0 + co + 8] = *(s16x8*)&th[ro][co + 8];
        *(s16x8*)&ol[(size_t)(n0 + ro) * R + k0 + co]     = *(s16x8*)&tl[ro][co];
        *(s16x8*)&ol[(size_t)(n0 + ro) * R + k0 + co + 8] = *(s16x8*)&tl[ro][co + 8];
    }
}

// ---------------------------------------------------------------------------
// fp32 [R,Cn] -> bf16 [Cn,R] transpose (single, for W_proj).
// ---------------------------------------------------------------------------
__global__ __launch_bounds__(256) void cvtT_bf16(
    const float* __restrict__ in, short* __restrict__ out, int R, int Cn)
{
    __shared__ short t[64][80];
    const int tid = threadIdx.x;
    const int k0 = blockIdx.y * 64;
    const int n0 = blockIdx.x * 64;
    {
        int rl = tid >> 4, cl = (tid & 15) * 4;
        #pragma unroll
        for (int i = 0; i < 4; i++) {
            int kr = rl + i * 16;
            float4 v = *(const float4*)&in[(size_t)(k0 + kr) * Cn + n0 + cl];
            t[cl + 0][kr] = (short)f2b(v.x);
            t[cl + 1][kr] = (short)f2b(v.y);
            t[cl + 2][kr] = (short)f2b(v.z);
            t[cl + 3][kr] = (short)f2b(v.w);
        }
    }
    __syncthreads();
    {
        int ro = tid >> 2, co = (tid & 3) * 16;
        *(s16x8*)&out[(size_t)(n0 + ro) * R + k0 + co]     = *(s16x8*)&t[ro][co];
        *(s16x8*)&out[(size_t)(n0 + ro) * R + k0 + co + 8] = *(s16x8*)&t[ro][co + 8];
    }
}

// ---------------------------------------------------------------------------
// qkv bf16x3 GEMM: acc = Ah*Bh + Ah*Bl + Al*Bh (fp32 accum).
// A = x fp32 (split in staging); B = pre-split WaTh/WaTl [N,K] bf16.
// 128x128 tile, BK=32, 4 waves 2x2, 4x4 16x16x32 MFMAs x3 per K-step.
// Q,K cols (n<2048) -> fp32 scatter; V cols -> bf16 scatter.
// ---------------------------------------------------------------------------
__global__ __launch_bounds__(256) void qkv_x3(
    const float* __restrict__ x,
    const short* __restrict__ BTh, const short* __restrict__ BTl,
    const float* __restrict__ bias,
    float* __restrict__ Qf, float* __restrict__ Kf, short* __restrict__ Vb)
{
    __shared__ short Ash[128][40], Asl[128][40];
    __shared__ short Bsh[128][40], Bsl[128][40];

    const int tid  = threadIdx.x;
    const int wave = tid >> 6, lane = tid & 63;
    const int wm = wave >> 1, wn = wave & 1;
    const int lm = lane & 15, lq = lane >> 4;
    const int m0 = blockIdx.y * 128, n0 = blockIdx.x * 128;
    const int lr = tid >> 2, lc = (tid & 3) * 8;

    f32x4 acc[4][4] = {};

    for (int k0 = 0; k0 < C_; k0 += 32) {
        __syncthreads();
        #pragma unroll
        for (int i = 0; i < 2; i++) {
            int row = i * 64 + lr;
            const float* xp = &x[(size_t)(m0 + row) * C_ + k0 + lc];
            float4 a0 = *(const float4*)xp;
            float4 a1 = *(const float4*)(xp + 4);
            float v[8] = {a0.x, a0.y, a0.z, a0.w, a1.x, a1.y, a1.z, a1.w};
            s16x8 hh, ll;
            #pragma unroll
            for (int j = 0; j < 8; j++) {
                unsigned short hb = f2b(v[j]);
                hh[j] = (short)hb;
                ll[j] = (short)f2b(v[j] - b2f(hb));
            }
            *(s16x8*)&Ash[row][lc] = hh;
            *(s16x8*)&Asl[row][lc] = ll;
            size_t brow = (size_t)(n0 + row) * C_ + k0 + lc;
            *(s16x8*)&Bsh[row][lc] = *(const s16x8*)&BTh[brow];
            *(s16x8*)&Bsl[row][lc] = *(const s16x8*)&BTl[brow];
        }
        __syncthreads();

        s16x8 ah[4], al[4], bh[4], bl[4];
        #pragma unroll
        for (int mi = 0; mi < 4; mi++) {
            ah[mi] = *(const s16x8*)&Ash[wm * 64 + mi * 16 + lm][lq * 8];
            al[mi] = *(const s16x8*)&Asl[wm * 64 + mi * 16 + lm][lq * 8];
        }
        #pragma unroll
        for (int nj = 0; nj < 4; nj++) {
            bh[nj] = *(const s16x8*)&Bsh[wn * 64 + nj * 16 + lm][lq * 8];
            bl[nj] = *(const s16x8*)&Bsl[wn * 64 + nj * 16 + lm][lq * 8];
        }
        #pragma unroll
        for (int mi = 0; mi < 4; mi++)
            #pragma unroll
            for (int nj = 0; nj < 4; nj++) {
                acc[mi][nj] = __builtin_amdgcn_mfma_f32_16x16x32_bf16(
                    ah[mi], bh[nj], acc[mi][nj], 0, 0, 0);
                acc[mi][nj] = __builtin_amdgcn_mfma_f32_16x16x32_bf16(
                    ah[mi], bl[nj], acc[mi][nj], 0, 0, 0);
                acc[mi][nj] = __builtin_amdgcn_mfma_f32_16x16x32_bf16(
                    al[mi], bh[nj], acc[mi][nj], 0, 0, 0);
            }
    }

    #pragma unroll
    for (int nj = 0; nj < 4; nj++) {
        int n = n0 + wn * 64 + nj * 16 + lm;
        float bv = bias[n];
        int which = n >> 10;           // 0=Q 1=K 2=V (uniform per block)
        int c = n & (C_ - 1);
        int h = c >> 6, d = c & (D_ - 1);
        #pragma unroll
        for (int mi = 0; mi < 4; mi++) {
            #pragma unroll
            for (int r = 0; r < 4; r++) {
                int m  = m0 + wm * 64 + mi * 16 + lq * 4 + r;
                int bb = m >> 11, t = m & (T_ - 1);
                float v = acc[mi][nj][r] + bv;
                size_t idx = (((size_t)bb * H_ + h) * T_ + t) * D_ + d;
                if (which == 0)      Qf[idx] = v;
                else if (which == 1) Kf[idx] = v;
                else                 Vb[idx] = (short)f2b(v);
            }
        }
    }
}

// ---------------------------------------------------------------------------
// proj: out fp32 [M,C] = Yb(bf16) @ WpT(bf16) + bias. Single bf16 MFMA.
// ---------------------------------------------------------------------------
__global__ __launch_bounds__(256) void proj_mfma(
    const short* __restrict__ A, const short* __restrict__ BT,
    const float* __restrict__ bias, float* __restrict__ out)
{
    __shared__ short As[128][40];
    __shared__ short Bs[128][40];

    const int tid  = threadIdx.x;
    const int wave = tid >> 6, lane = tid & 63;
    const int wm = wave >> 1, wn = wave & 1;
    const int lm = lane & 15, lq = lane >> 4;
    const int m0 = blockIdx.y * 128, n0 = blockIdx.x * 128;
    const int lr = tid >> 2, lc = (tid & 3) * 8;

    f32x4 acc[4][4] = {};

    for (int k0 = 0; k0 < C_; k0 += 32) {
        __syncthreads();
        #pragma unroll
        for (int i = 0; i < 2; i++) {
            *(s16x8*)&As[i * 64 + lr][lc] =
                *(const s16x8*)&A[(size_t)(m0 + i * 64 + lr) * C_ + k0 + lc];
            *(s16x8*)&Bs[i * 64 + lr][lc] =
                *(const s16x8*)&BT[(size_t)(n0 + i * 64 + lr) * C_ + k0 + lc];
        }
        __syncthreads();

        s16x8 af[4], bfr[4];
        #pragma unroll
        for (int mi = 0; mi < 4; mi++)
            af[mi] = *(const s16x8*)&As[wm * 64 + mi * 16 + lm][lq * 8];
        #pragma unroll
        for (int nj = 0; nj < 4; nj++)
            bfr[nj] = *(const s16x8*)&Bs[wn * 64 + nj * 16 + lm][lq * 8];
        #pragma unroll
        for (int mi = 0; mi < 4; mi++)
            #pragma unroll
            for (int nj = 0; nj < 4; nj++)
                acc[mi][nj] = __builtin_amdgcn_mfma_f32_16x16x32_bf16(
                    af[mi], bfr[nj], acc[mi][nj], 0, 0, 0);
    }

    #pragma unroll
    for (int nj = 0; nj < 4; nj++) {
        int n = n0 + wn * 64 + nj * 16 + lm;
        float bv = bias[n];
        #pragma unroll
        for (int mi = 0; mi < 4; mi++) {
            #pragma unroll
            for (int r = 0; r < 4; r++) {
                int m = m0 + wm * 64 + mi * 16 + lq * 4 + r;
                out[(size_t)m * C_ + n] = acc[mi][nj][r] + bv;
            }
        }
    }
}

// ---------------------------------------------------------------------------
// Flash-style causal attention, fp32 VALU. Q,K fp32; V bf16; out Yb bf16.
// Faithful scale: att = (q.k) * sqrt(D) = dot * 8.0
// ---------------------------------------------------------------------------
__global__ __launch_bounds__(256) void attn_tiled(
    const float* __restrict__ Q, const float* __restrict__ K,
    const short* __restrict__ V, short* __restrict__ Yb)
{
    __shared__ float QsT[64][66];
    __shared__ float KsT[64][66];   // reused as P^T
    __shared__ float Vs [64][66];

    const int tid = threadIdx.x;
    const int tx  = tid & 15;
    const int ty  = tid >> 4;
    const int tx4 = tx * 4, ty4 = ty * 4;
    const int bh  = blockIdx.y;
    const int b   = bh >> 4, h = bh & (H_ - 1);
    const size_t base = (size_t)bh * T_ * D_;

    for (int half = 0; half < 2; half++) {
        const int qt = (half == 0) ? blockIdx.x : 31 - blockIdx.x;
        const int q0 = qt * 64;

        __syncthreads();
        #pragma unroll
        for (int i = 0; i < 4; i++) {
            int row = i * 16 + ty;
            float4 a4 = *(const float4*)&Q[base + (size_t)(q0 + row) * D_ + tx4];
            QsT[tx4 + 0][row] = a4.x; QsT[tx4 + 1][row] = a4.y;
            QsT[tx4 + 2][row] = a4.z; QsT[tx4 + 3][row] = a4.w;
        }

        float m[4], l[4], O[4][4];
        #pragma unroll
        for (int i = 0; i < 4; i++) {
            m[i] = -INFINITY; l[i] = 0.f;
            #pragma unroll
            for (int j = 0; j < 4; j++) O[i][j] = 0.f;
        }

        for (int kt = 0; kt <= qt; kt++) {
            __syncthreads();
            #pragma unroll
            for (int i = 0; i < 4; i++) {
                int row = i * 16 + ty;
                float4 k4 = *(const float4*)&K[base + (size_t)(kt * 64 + row) * D_ + tx4];
                ushort4 v4 = *(const ushort4*)&V[base + (size_t)(kt * 64 + row) * D_ + tx4];
                KsT[tx4 + 0][row] = k4.x; KsT[tx4 + 1][row] = k4.y;
                KsT[tx4 + 2][row] = k4.z; KsT[tx4 + 3][row] = k4.w;
                Vs[row][tx4 + 0] = b2f(v4.x); Vs[row][tx4 + 1] = b2f(v4.y);
                Vs[row][tx4 + 2] = b2f(v4.z); Vs[row][tx4 + 3] = b2f(v4.w);
            }
            __syncthreads();

            float s[4][4] = {};
            #pragma unroll 8
            for (int k = 0; k < 64; k++) {
                float2 a01 = *(const float2*)&QsT[k][ty4];
                float2 a23 = *(const float2*)&QsT[k][ty4 + 2];
                float2 b01 = *(const float2*)&KsT[k][tx4];
                float2 b23 = *(const float2*)&KsT[k][tx4 + 2];
                float a[4] = {a01.x, a01.y, a23.x, a23.y};
                float bb[4] = {b01.x, b01.y, b23.x, b23.y};
                #pragma unroll
                for (int i = 0; i < 4; i++)
                    #pragma unroll
                    for (int j = 0; j < 4; j++) s[i][j] += a[i] * bb[j];
            }

            #pragma unroll
            for (int i = 0; i < 4; i++)
                #pragma unroll
                for (int j = 0; j < 4; j++) {
                    s[i][j] *= 8.0f;
                    if (kt == qt && (tx4 + j) > (ty4 + i)) s[i][j] = -INFINITY;
                }

            float mnew[4], alpha[4], rsum[4];
            #pragma unroll
            for (int i = 0; i < 4; i++) {
                float rm = fmaxf(fmaxf(s[i][0], s[i][1]), fmaxf(s[i][2], s[i][3]));
                #pragma unroll
                for (int off = 1; off < 16; off <<= 1)
                    rm = fmaxf(rm, __shfl_xor(rm, off, 64));
                mnew[i]  = fmaxf(m[i], rm);
                alpha[i] = __expf(m[i] - mnew[i]);
                float rs = 0.f;
                #pragma unroll
                for (int j = 0; j < 4; j++) {
                    s[i][j] = __expf(s[i][j] - mnew[i]);
                    rs += s[i][j];
                }
                #pragma unroll
                for (int off = 1; off < 16; off <<= 1)
                    rs += __shfl_xor(rs, off, 64);
                rsum[i] = rs;
            }
            #pragma unroll
            for (int i = 0; i < 4; i++) {
                l[i] = l[i] * alpha[i] + rsum[i];
                m[i] = mnew[i];
                #pragma unroll
                for (int j = 0; j < 4; j++) O[i][j] *= alpha[i];
            }

            __syncthreads();
            #pragma unroll
            for (int i = 0; i < 4; i++)
                #pragma unroll
                for (int j = 0; j < 4; j++)
                    KsT[tx4 + j][ty4 + i] = s[i][j];
            __syncthreads();

            #pragma unroll 8
            for (int kk = 0; kk < 64; kk++) {
                float2 a01 = *(const float2*)&KsT[kk][ty4];
                float2 a23 = *(const float2*)&KsT[kk][ty4 + 2];
                float2 b01 = *(const float2*)&Vs[kk][tx4];
                float2 b23 = *(const float2*)&Vs[kk][tx4 + 2];
                float a[4] = {a01.x, a01.y, a23.x, a23.y};
                float bb[4] = {b01.x, b01.y, b23.x, b23.y};
                #pragma unroll
                for (int i = 0; i < 4; i++)
                    #pragma unroll
                    for (int j = 0; j < 4; j++) O[i][j] += a[i] * bb[j];
            }
        }

        #pragma unroll
        for (int i = 0; i < 4; i++) {
            float inv = 1.0f / l[i];
            ushort4 o4;
            o4.x = f2b(O[i][0] * inv); o4.y = f2b(O[i][1] * inv);
            o4.z = f2b(O[i][2] * inv); o4.w = f2b(O[i][3] * inv);
            *(ushort4*)&Yb[((size_t)b * T_ + (q0 + ty4 + i)) * C_ + h * D_ + tx4] = o4;
        }
    }
}

// ---------------------------------------------------------------------------
extern "C" void kernel_launch(void* const* d_in, const int* in_sizes, int n_in,
                              void* d_out, int out_size, void* d_ws, size_t ws_size,
                              hipStream_t stream)
{
    const float* x      = (const float*)d_in[0];
    const float* W_attn = (const float*)d_in[1];
    const float* b_attn = (const float*)d_in[2];
    const float* W_proj = (const float*)d_in[3];
    const float* b_proj = (const float*)d_in[4];
    float* out = (float*)d_out;

    char* ws = (char*)d_ws;
    const size_t MB = 1024 * 1024;
    float* Qf   = (float*)(ws);            // 16 MB  [ 0,16)
    float* Kf   = (float*)(ws + 16 * MB);  // 16 MB  [16,32)
    short* Vb   = (short*)(ws + 32 * MB);  //  8 MB  [32,40)
    short* WaTh = (short*)(ws + 40 * MB);  //  6 MB  [40,46)  [3072,1024]
    short* WaTl = (short*)(ws + 46 * MB);  //  6 MB  [46,52)
    short* WpT  = (short*)(ws + 52 * MB);  //  2 MB  [52,54)  [1024,1024]
    short* Yb   = (short*)(ws + 54 * MB);  //  8 MB  [54,62)

    cvtT_split<<<dim3(N3_ / 64, C_ / 64), 256, 0, stream>>>(W_attn, WaTh, WaTl, C_, N3_);
    cvtT_bf16 <<<dim3(C_ / 64, C_ / 64), 256, 0, stream>>>(W_proj, WpT, C_, C_);

    qkv_x3    <<<dim3(N3_ / 128, M_ / 128), 256, 0, stream>>>(x, WaTh, WaTl,
                                                              b_attn, Qf, Kf, Vb);
    attn_tiled<<<dim3(16, 32), 256, 0, stream>>>(Qf, Kf, Vb, Yb);
    proj_mfma <<<dim3(C_ / 128, M_ / 128), 256, 0, stream>>>(Yb, WpT, b_proj, out);
}

// Round 8
// 332.781 us; speedup vs baseline: 16.0470x; 1.6606x over previous
//
#include <hip/hip_runtime.h>
#include <hip/hip_bf16.h>

// Problem: CausalSelfAttention  B=2, T=2048, C=1024, H=16, D=64
// Round 8: MFMA flash attention. qkv writes pre-split Qh/Ql/Kh/Kl (bf16x2 =
// ~2^-17 precision for the softmax-critical S path) + Vb. Attention computes
// S = Qh*Kh + Qh*Kl + Ql*Kh on MFMA (fp32 accum), fp32 online softmax,
// P in bf16 via wave-private LDS slab, PV on MFMA.
// ws (62 MB): Qh 8|Ql 8|Kh 8|Kl 8|Vb 8|WaTh 6|WaTl 6|WpT 2|Yb 8

#define B_  2
#define T_  2048
#define C_  1024
#define H_  16
#define D_  64
#define M_  (B_ * T_)      // 4096
#define N3_ (3 * C_)       // 3072

typedef __attribute__((ext_vector_type(8))) short s16x8;
typedef __attribute__((ext_vector_type(4))) float f32x4;

__device__ __forceinline__ float b2f(unsigned short u) {
    return __uint_as_float(((unsigned)u) << 16);
}
__device__ __forceinline__ unsigned short f2b(float f) {   // RNE bf16 round
    unsigned u = __float_as_uint(f);
    return (unsigned short)((u + 0x7FFFu + ((u >> 16) & 1u)) >> 16);
}

// ---------------------------------------------------------------------------
// fp32 [R,Cn] -> (hi,lo) bf16 [Cn,R] transpose+split. grid (Cn/64, R/64).
// ---------------------------------------------------------------------------
__global__ __launch_bounds__(256) void cvtT_split(
    const float* __restrict__ in, short* __restrict__ oh, short* __restrict__ ol,
    int R, int Cn)
{
    __shared__ short th[64][80];
    __shared__ short tl[64][80];
    const int tid = threadIdx.x;
    const int k0 = blockIdx.y * 64;
    const int n0 = blockIdx.x * 64;
    {
        int rl = tid >> 4, cl = (tid & 15) * 4;
        #pragma unroll
        for (int i = 0; i < 4; i++) {
            int kr = rl + i * 16;
            float4 v4 = *(const float4*)&in[(size_t)(k0 + kr) * Cn + n0 + cl];
            float v[4] = {v4.x, v4.y, v4.z, v4.w};
            #pragma unroll
            for (int j = 0; j < 4; j++) {
                unsigned short hb = f2b(v[j]);
                th[cl + j][kr] = (short)hb;
                tl[cl + j][kr] = (short)f2b(v[j] - b2f(hb));
            }
        }
    }
    __syncthreads();
    {
        int ro = tid >> 2, co = (tid & 3) * 16;
        *(s16x8*)&oh[(size_t)(n0 + ro) * R + k0 + co]     = *(s16x8*)&th[ro][co];
        *(s16x8*)&oh[(size_t)(n0 + ro) * R + k0 + co + 8] = *(s16x8*)&th[ro][co + 8];
        *(s16x8*)&ol[(size_t)(n0 + ro) * R + k0 + co]     = *(s16x8*)&tl[ro][co];
        *(s16x8*)&ol[(size_t)(n0 + ro) * R + k0 + co + 8] = *(s16x8*)&tl[ro][co + 8];
    }
}

// ---------------------------------------------------------------------------
// fp32 [R,Cn] -> bf16 [Cn,R] transpose (single, for W_proj).
// ---------------------------------------------------------------------------
__global__ __launch_bounds__(256) void cvtT_bf16(
    const float* __restrict__ in, short* __restrict__ out, int R, int Cn)
{
    __shared__ short t[64][80];
    const int tid = threadIdx.x;
    const int k0 = blockIdx.y * 64;
    const int n0 = blockIdx.x * 64;
    {
        int rl = tid >> 4, cl = (tid & 15) * 4;
        #pragma unroll
        for (int i = 0; i < 4; i++) {
            int kr = rl + i * 16;
            float4 v = *(const float4*)&in[(size_t)(k0 + kr) * Cn + n0 + cl];
            t[cl + 0][kr] = (short)f2b(v.x);
            t[cl + 1][kr] = (short)f2b(v.y);
            t[cl + 2][kr] = (short)f2b(v.z);
            t[cl + 3][kr] = (short)f2b(v.w);
        }
    }
    __syncthreads();
    {
        int ro = tid >> 2, co = (tid & 3) * 16;
        *(s16x8*)&out[(size_t)(n0 + ro) * R + k0 + co]     = *(s16x8*)&t[ro][co];
        *(s16x8*)&out[(size_t)(n0 + ro) * R + k0 + co + 8] = *(s16x8*)&t[ro][co + 8];
    }
}

// ---------------------------------------------------------------------------
// qkv bf16x3 GEMM: acc = Ah*Bh + Ah*Bl + Al*Bh (fp32 accum).
// Q,K cols -> hi/lo bf16 split scatter; V cols -> bf16 scatter.
// ---------------------------------------------------------------------------
__global__ __launch_bounds__(256) void qkv_x3(
    const float* __restrict__ x,
    const short* __restrict__ BTh, const short* __restrict__ BTl,
    const float* __restrict__ bias,
    short* __restrict__ Qh, short* __restrict__ Ql,
    short* __restrict__ Kh, short* __restrict__ Kl,
    short* __restrict__ Vb)
{
    __shared__ short Ash[128][40], Asl[128][40];
    __shared__ short Bsh[128][40], Bsl[128][40];

    const int tid  = threadIdx.x;
    const int wave = tid >> 6, lane = tid & 63;
    const int wm = wave >> 1, wn = wave & 1;
    const int lm = lane & 15, lq = lane >> 4;
    const int m0 = blockIdx.y * 128, n0 = blockIdx.x * 128;
    const int lr = tid >> 2, lc = (tid & 3) * 8;

    f32x4 acc[4][4] = {};

    for (int k0 = 0; k0 < C_; k0 += 32) {
        __syncthreads();
        #pragma unroll
        for (int i = 0; i < 2; i++) {
            int row = i * 64 + lr;
            const float* xp = &x[(size_t)(m0 + row) * C_ + k0 + lc];
            float4 a0 = *(const float4*)xp;
            float4 a1 = *(const float4*)(xp + 4);
            float v[8] = {a0.x, a0.y, a0.z, a0.w, a1.x, a1.y, a1.z, a1.w};
            s16x8 hh, ll;
            #pragma unroll
            for (int j = 0; j < 8; j++) {
                unsigned short hb = f2b(v[j]);
                hh[j] = (short)hb;
                ll[j] = (short)f2b(v[j] - b2f(hb));
            }
            *(s16x8*)&Ash[row][lc] = hh;
            *(s16x8*)&Asl[row][lc] = ll;
            size_t brow = (size_t)(n0 + row) * C_ + k0 + lc;
            *(s16x8*)&Bsh[row][lc] = *(const s16x8*)&BTh[brow];
            *(s16x8*)&Bsl[row][lc] = *(const s16x8*)&BTl[brow];
        }
        __syncthreads();

        s16x8 ah[4], al[4], bh[4], bl[4];
        #pragma unroll
        for (int mi = 0; mi < 4; mi++) {
            ah[mi] = *(const s16x8*)&Ash[wm * 64 + mi * 16 + lm][lq * 8];
            al[mi] = *(const s16x8*)&Asl[wm * 64 + mi * 16 + lm][lq * 8];
        }
        #pragma unroll
        for (int nj = 0; nj < 4; nj++) {
            bh[nj] = *(const s16x8*)&Bsh[wn * 64 + nj * 16 + lm][lq * 8];
            bl[nj] = *(const s16x8*)&Bsl[wn * 64 + nj * 16 + lm][lq * 8];
        }
        #pragma unroll
        for (int mi = 0; mi < 4; mi++)
            #pragma unroll
            for (int nj = 0; nj < 4; nj++) {
                acc[mi][nj] = __builtin_amdgcn_mfma_f32_16x16x32_bf16(
                    ah[mi], bh[nj], acc[mi][nj], 0, 0, 0);
                acc[mi][nj] = __builtin_amdgcn_mfma_f32_16x16x32_bf16(
                    ah[mi], bl[nj], acc[mi][nj], 0, 0, 0);
                acc[mi][nj] = __builtin_amdgcn_mfma_f32_16x16x32_bf16(
                    al[mi], bh[nj], acc[mi][nj], 0, 0, 0);
            }
    }

    #pragma unroll
    for (int nj = 0; nj < 4; nj++) {
        int n = n0 + wn * 64 + nj * 16 + lm;
        float bv = bias[n];
        int which = n >> 10;           // 0=Q 1=K 2=V
        int c = n & (C_ - 1);
        int h = c >> 6, d = c & (D_ - 1);
        #pragma unroll
        for (int mi = 0; mi < 4; mi++) {
            #pragma unroll
            for (int r = 0; r < 4; r++) {
                int m  = m0 + wm * 64 + mi * 16 + lq * 4 + r;
                int bb = m >> 11, t = m & (T_ - 1);
                float v = acc[mi][nj][r] + bv;
                size_t idx = (((size_t)bb * H_ + h) * T_ + t) * D_ + d;
                if (which == 2) {
                    Vb[idx] = (short)f2b(v);
                } else {
                    unsigned short hb = f2b(v);
                    unsigned short lb = f2b(v - b2f(hb));
                    if (which == 0) { Qh[idx] = (short)hb; Ql[idx] = (short)lb; }
                    else            { Kh[idx] = (short)hb; Kl[idx] = (short)lb; }
                }
            }
        }
    }
}

// ---------------------------------------------------------------------------
// proj: out fp32 [M,C] = Yb(bf16) @ WpT(bf16) + bias. Single bf16 MFMA.
// ---------------------------------------------------------------------------
__global__ __launch_bounds__(256) void proj_mfma(
    const short* __restrict__ A, const short* __restrict__ BT,
    const float* __restrict__ bias, float* __restrict__ out)
{
    __shared__ short As[128][40];
    __shared__ short Bs[128][40];

    const int tid  = threadIdx.x;
    const int wave = tid >> 6, lane = tid & 63;
    const int wm = wave >> 1, wn = wave & 1;
    const int lm = lane & 15, lq = lane >> 4;
    const int m0 = blockIdx.y * 128, n0 = blockIdx.x * 128;
    const int lr = tid >> 2, lc = (tid & 3) * 8;

    f32x4 acc[4][4] = {};

    for (int k0 = 0; k0 < C_; k0 += 32) {
        __syncthreads();
        #pragma unroll
        for (int i = 0; i < 2; i++) {
            *(s16x8*)&As[i * 64 + lr][lc] =
                *(const s16x8*)&A[(size_t)(m0 + i * 64 + lr) * C_ + k0 + lc];
            *(s16x8*)&Bs[i * 64 + lr][lc] =
                *(const s16x8*)&BT[(size_t)(n0 + i * 64 + lr) * C_ + k0 + lc];
        }
        __syncthreads();

        s16x8 af[4], bfr[4];
        #pragma unroll
        for (int mi = 0; mi < 4; mi++)
            af[mi] = *(const s16x8*)&As[wm * 64 + mi * 16 + lm][lq * 8];
        #pragma unroll
        for (int nj = 0; nj < 4; nj++)
            bfr[nj] = *(const s16x8*)&Bs[wn * 64 + nj * 16 + lm][lq * 8];
        #pragma unroll
        for (int mi = 0; mi < 4; mi++)
            #pragma unroll
            for (int nj = 0; nj < 4; nj++)
                acc[mi][nj] = __builtin_amdgcn_mfma_f32_16x16x32_bf16(
                    af[mi], bfr[nj], acc[mi][nj], 0, 0, 0);
    }

    #pragma unroll
    for (int nj = 0; nj < 4; nj++) {
        int n = n0 + wn * 64 + nj * 16 + lm;
        float bv = bias[n];
        #pragma unroll
        for (int mi = 0; mi < 4; mi++) {
            #pragma unroll
            for (int r = 0; r < 4; r++) {
                int m = m0 + wm * 64 + mi * 16 + lq * 4 + r;
                out[(size_t)m * C_ + n] = acc[mi][nj][r] + bv;
            }
        }
    }
}

// ---------------------------------------------------------------------------
// MFMA flash attention. Block = 4 waves; wave w owns q-rows [w*16, w*16+16)
// of a 64-row q-tile, all 64 keys of each k-tile. Balanced causal pairing:
// block handles qt and 31-qt. S via bf16x3 MFMA, softmax fp32, P bf16 via
// wave-private LDS slab (C-layout -> A-layout), PV via MFMA.
// Faithful scale: S = (q.k) * 8.
// ---------------------------------------------------------------------------
__global__ __launch_bounds__(256) void attn_mfma(
    const short* __restrict__ Qh, const short* __restrict__ Ql,
    const short* __restrict__ Kh, const short* __restrict__ Kl,
    const short* __restrict__ V,  short* __restrict__ Yb)
{
    __shared__ short Qsh[64][72], Qsl[64][72];   // [q][d]
    __shared__ short Ksh[64][72], Ksl[64][72];   // [key][d]
    __shared__ short Vt [64][72];                // [d][key]
    __shared__ short Ps [4][16][72];             // per-wave P [qrow][key]

    const int tid  = threadIdx.x;
    const int wave = tid >> 6, lane = tid & 63;
    const int lm   = lane & 15, quad = lane >> 4;
    const int bh   = blockIdx.y;
    const int b    = bh >> 4, h = bh & (H_ - 1);
    const size_t base = (size_t)bh * T_ * D_;

    for (int half = 0; half < 2; half++) {
        const int qt = (half == 0) ? blockIdx.x : 31 - blockIdx.x;
        const int q0 = qt * 64;

        __syncthreads();   // prev q-tile readers done before Qs overwrite
        #pragma unroll
        for (int i = 0; i < 2; i++) {      // stage Q hi/lo (64x64)
            int c = i * 256 + tid;
            int row = c >> 3, ch = (c & 7) * 8;
            size_t g = base + (size_t)(q0 + row) * D_ + ch;
            *(s16x8*)&Qsh[row][ch] = *(const s16x8*)&Qh[g];
            *(s16x8*)&Qsl[row][ch] = *(const s16x8*)&Ql[g];
        }
        __syncthreads();

        // hoist Q A-frags for this wave's 16 q-rows
        s16x8 aqh[2], aql[2];
        #pragma unroll
        for (int kc = 0; kc < 2; kc++) {
            aqh[kc] = *(const s16x8*)&Qsh[wave * 16 + lm][kc * 32 + quad * 8];
            aql[kc] = *(const s16x8*)&Qsl[wave * 16 + lm][kc * 32 + quad * 8];
        }

        float mrow[4], lrow[4];
        f32x4 O[4] = {};
        #pragma unroll
        for (int r = 0; r < 4; r++) { mrow[r] = -INFINITY; lrow[r] = 0.f; }

        for (int kt = 0; kt <= qt; kt++) {
            __syncthreads();   // prev S/PV readers done before K/Vt overwrite
            #pragma unroll
            for (int i = 0; i < 2; i++) {  // stage K hi/lo (64x64)
                int c = i * 256 + tid;
                int row = c >> 3, ch = (c & 7) * 8;
                size_t g = base + (size_t)(kt * 64 + row) * D_ + ch;
                *(s16x8*)&Ksh[row][ch] = *(const s16x8*)&Kh[g];
                *(s16x8*)&Ksl[row][ch] = *(const s16x8*)&Kl[g];
            }
            #pragma unroll
            for (int i = 0; i < 2; i++) {  // stage V transposed -> Vt[d][key]
                int c = i * 256 + tid;
                int dc = c & 7, key = c >> 3;
                s16x8 v8 = *(const s16x8*)&V[base + (size_t)(kt * 64 + key) * D_ + dc * 8];
                #pragma unroll
                for (int j = 0; j < 8; j++) {   // stagger: 2-way banks only
                    int e = (j + dc) & 7;
                    Vt[dc * 8 + e][key] = v8[e];
                }
            }
            __syncthreads();

            // ---- S = Q K^T (bf16x3), wave: 16q x 64k as 4 16x16 tiles ----
            f32x4 S[4] = {};
            #pragma unroll
            for (int t = 0; t < 4; t++) {
                #pragma unroll
                for (int kc = 0; kc < 2; kc++) {
                    s16x8 kh8 = *(const s16x8*)&Ksh[t * 16 + lm][kc * 32 + quad * 8];
                    s16x8 kl8 = *(const s16x8*)&Ksl[t * 16 + lm][kc * 32 + quad * 8];
                    S[t] = __builtin_amdgcn_mfma_f32_16x16x32_bf16(aqh[kc], kh8, S[t], 0, 0, 0);
                    S[t] = __builtin_amdgcn_mfma_f32_16x16x32_bf16(aqh[kc], kl8, S[t], 0, 0, 0);
                    S[t] = __builtin_amdgcn_mfma_f32_16x16x32_bf16(aql[kc], kh8, S[t], 0, 0, 0);
                }
            }

            // scale + causal mask (C layout: col=lm -> key, row=quad*4+r -> q)
            #pragma unroll
            for (int t = 0; t < 4; t++)
                #pragma unroll
                for (int r = 0; r < 4; r++) {
                    float v = S[t][r] * 8.0f;
                    if (kt == qt && (t * 16 + lm) > (wave * 16 + quad * 4 + r))
                        v = -INFINITY;
                    S[t][r] = v;
                }

            // ---- online softmax (wave-private rows) ----
            float alpha[4];
            #pragma unroll
            for (int r = 0; r < 4; r++) {
                float rm = fmaxf(fmaxf(S[0][r], S[1][r]), fmaxf(S[2][r], S[3][r]));
                #pragma unroll
                for (int off = 1; off < 16; off <<= 1)
                    rm = fmaxf(rm, __shfl_xor(rm, off, 64));
                float mnew = fmaxf(mrow[r], rm);
                alpha[r] = __expf(mrow[r] - mnew);
                mrow[r] = mnew;
                float rs = 0.f;
                #pragma unroll
                for (int t = 0; t < 4; t++) {
                    S[t][r] = __expf(S[t][r] - mnew);
                    rs += S[t][r];
                }
                #pragma unroll
                for (int off = 1; off < 16; off <<= 1)
                    rs += __shfl_xor(rs, off, 64);
                lrow[r] = lrow[r] * alpha[r] + rs;
            }
            #pragma unroll
            for (int t = 0; t < 4; t++)
                #pragma unroll
                for (int r = 0; r < 4; r++) O[t][r] *= alpha[r];

            // ---- P (C-layout) -> wave-private LDS slab (A-layout source) ----
            #pragma unroll
            for (int t = 0; t < 4; t++)
                #pragma unroll
                for (int r = 0; r < 4; r++)
                    Ps[wave][quad * 4 + r][t * 16 + lm] = (short)f2b(S[t][r]);
            // wave-private: no barrier; lgkmcnt ordering suffices

            // ---- O += P V ----
            s16x8 ap[2];
            #pragma unroll
            for (int kc = 0; kc < 2; kc++)
                ap[kc] = *(const s16x8*)&Ps[wave][lm][kc * 32 + quad * 8];
            #pragma unroll
            for (int t = 0; t < 4; t++) {
                #pragma unroll
                for (int kc = 0; kc < 2; kc++) {
                    s16x8 bv = *(const s16x8*)&Vt[t * 16 + lm][kc * 32 + quad * 8];
                    O[t] = __builtin_amdgcn_mfma_f32_16x16x32_bf16(ap[kc], bv, O[t], 0, 0, 0);
                }
            }
        }

        // ---- epilogue: normalize, write Yb[b, q, h*64+d] bf16 ----
        #pragma unroll
        for (int t = 0; t < 4; t++)
            #pragma unroll
            for (int r = 0; r < 4; r++) {
                int q = q0 + wave * 16 + quad * 4 + r;
                int d = t * 16 + lm;
                Yb[((size_t)b * T_ + q) * C_ + h * D_ + d] =
                    (short)f2b(O[t][r] / lrow[r]);
            }
    }
}

// ---------------------------------------------------------------------------
extern "C" void kernel_launch(void* const* d_in, const int* in_sizes, int n_in,
                              void* d_out, int out_size, void* d_ws, size_t ws_size,
                              hipStream_t stream)
{
    const float* x      = (const float*)d_in[0];
    const float* W_attn = (const float*)d_in[1];
    const float* b_attn = (const float*)d_in[2];
    const float* W_proj = (const float*)d_in[3];
    const float* b_proj = (const float*)d_in[4];
    float* out = (float*)d_out;

    char* ws = (char*)d_ws;
    const size_t MB = 1024 * 1024;
    short* Qh   = (short*)(ws);            // 8 MB  [ 0, 8)
    short* Ql   = (short*)(ws +  8 * MB);  // 8 MB  [ 8,16)
    short* Kh   = (short*)(ws + 16 * MB);  // 8 MB  [16,24)
    short* Kl   = (short*)(ws + 24 * MB);  // 8 MB  [24,32)
    short* Vb   = (short*)(ws + 32 * MB);  // 8 MB  [32,40)
    short* WaTh = (short*)(ws + 40 * MB);  // 6 MB  [40,46)
    short* WaTl = (short*)(ws + 46 * MB);  // 6 MB  [46,52)
    short* WpT  = (short*)(ws + 52 * MB);  // 2 MB  [52,54)
    short* Yb   = (short*)(ws + 54 * MB);  // 8 MB  [54,62)

    cvtT_split<<<dim3(N3_ / 64, C_ / 64), 256, 0, stream>>>(W_attn, WaTh, WaTl, C_, N3_);
    cvtT_bf16 <<<dim3(C_ / 64, C_ / 64), 256, 0, stream>>>(W_proj, WpT, C_, C_);

    qkv_x3   <<<dim3(N3_ / 128, M_ / 128), 256, 0, stream>>>(x, WaTh, WaTl, b_attn,
                                                             Qh, Ql, Kh, Kl, Vb);
    attn_mfma<<<dim3(16, 32), 256, 0, stream>>>(Qh, Ql, Kh, Kl, Vb, Yb);
    proj_mfma<<<dim3(C_ / 128, M_ / 128), 256, 0, stream>>>(Yb, WpT, b_proj, out);
}

// Round 9
// 301.615 us; speedup vs baseline: 17.7051x; 1.1033x over previous
//
#include <hip/hip_runtime.h>
#include <hip/hip_bf16.h>

// Problem: CausalSelfAttention  B=2, T=2048, C=1024, H=16, D=64
// Round 9: m97-style GEMMs. x pre-split once; qkv split into qk (bf16x3) and
// v (bf16x1); all GEMM staging via global_load_lds width=16 into unpadded
// [128][32] LDS. Attention (MFMA flash, bf16x3 S-path) unchanged from r8.
// ws (62 MB): Qh 8|Ql 8|Kh 8|Kl 8|xh 8(->Yb)|xl 8(->Vb)|WaTh 6|WaTl 6|WpT 2

#define B_  2
#define T_  2048
#define C_  1024
#define H_  16
#define D_  64
#define M_  (B_ * T_)      // 4096
#define N3_ (3 * C_)       // 3072

typedef __attribute__((ext_vector_type(8))) short s16x8;
typedef __attribute__((ext_vector_type(4))) float f32x4;

typedef const __attribute__((address_space(1))) unsigned int gu32_t;
typedef __attribute__((address_space(3))) unsigned int lu32_t;

__device__ __forceinline__ void gload_lds16(const short* g, short* l) {
    // async global->LDS DMA, 16 B/lane; LDS dest = wave-uniform base + lane*16
    __builtin_amdgcn_global_load_lds((gu32_t*)g, (lu32_t*)l, 16, 0, 0);
}

__device__ __forceinline__ float b2f(unsigned short u) {
    return __uint_as_float(((unsigned)u) << 16);
}
__device__ __forceinline__ unsigned short f2b(float f) {   // RNE bf16 round
    unsigned u = __float_as_uint(f);
    return (unsigned short)((u + 0x7FFFu + ((u >> 16) & 1u)) >> 16);
}

// ---------------------------------------------------------------------------
// fp32 -> (hi, lo) bf16 split. n multiple of 2048.
// ---------------------------------------------------------------------------
__global__ __launch_bounds__(256) void cvt_split(
    const float* __restrict__ in, short* __restrict__ oh, short* __restrict__ ol, int n)
{
    int i = (blockIdx.x * 256 + threadIdx.x) * 8;
    if (i >= n) return;
    float4 a = *(const float4*)&in[i];
    float4 b = *(const float4*)&in[i + 4];
    float v[8] = {a.x, a.y, a.z, a.w, b.x, b.y, b.z, b.w};
    s16x8 h, l;
    #pragma unroll
    for (int j = 0; j < 8; j++) {
        unsigned short hb = f2b(v[j]);
        h[j] = (short)hb;
        l[j] = (short)f2b(v[j] - b2f(hb));
    }
    *(s16x8*)&oh[i] = h;
    *(s16x8*)&ol[i] = l;
}

// ---------------------------------------------------------------------------
// fp32 [R,Cn] -> (hi,lo) bf16 [Cn,R] transpose+split. grid (Cn/64, R/64).
// ---------------------------------------------------------------------------
__global__ __launch_bounds__(256) void cvtT_split(
    const float* __restrict__ in, short* __restrict__ oh, short* __restrict__ ol,
    int R, int Cn)
{
    __shared__ short th[64][80];
    __shared__ short tl[64][80];
    const int tid = threadIdx.x;
    const int k0 = blockIdx.y * 64;
    const int n0 = blockIdx.x * 64;
    {
        int rl = tid >> 4, cl = (tid & 15) * 4;
        #pragma unroll
        for (int i = 0; i < 4; i++) {
            int kr = rl + i * 16;
            float4 v4 = *(const float4*)&in[(size_t)(k0 + kr) * Cn + n0 + cl];
            float v[4] = {v4.x, v4.y, v4.z, v4.w};
            #pragma unroll
            for (int j = 0; j < 4; j++) {
                unsigned short hb = f2b(v[j]);
                th[cl + j][kr] = (short)hb;
                tl[cl + j][kr] = (short)f2b(v[j] - b2f(hb));
            }
        }
    }
    __syncthreads();
    {
        int ro = tid >> 2, co = (tid & 3) * 16;
        *(s16x8*)&oh[(size_t)(n0 + ro) * R + k0 + co]     = *(s16x8*)&th[ro][co];
        *(s16x8*)&oh[(size_t)(n0 + ro) * R + k0 + co + 8] = *(s16x8*)&th[ro][co + 8];
        *(s16x8*)&ol[(size_t)(n0 + ro) * R + k0 + co]     = *(s16x8*)&tl[ro][co];
        *(s16x8*)&ol[(size_t)(n0 + ro) * R + k0 + co + 8] = *(s16x8*)&tl[ro][co + 8];
    }
}

// ---------------------------------------------------------------------------
// fp32 [R,Cn] -> bf16 [Cn,R] transpose (single, for W_proj).
// ---------------------------------------------------------------------------
__global__ __launch_bounds__(256) void cvtT_bf16(
    const float* __restrict__ in, short* __restrict__ out, int R, int Cn)
{
    __shared__ short t[64][80];
    const int tid = threadIdx.x;
    const int k0 = blockIdx.y * 64;
    const int n0 = blockIdx.x * 64;
    {
        int rl = tid >> 4, cl = (tid & 15) * 4;
        #pragma unroll
        for (int i = 0; i < 4; i++) {
            int kr = rl + i * 16;
            float4 v = *(const float4*)&in[(size_t)(k0 + kr) * Cn + n0 + cl];
            t[cl + 0][kr] = (short)f2b(v.x);
            t[cl + 1][kr] = (short)f2b(v.y);
            t[cl + 2][kr] = (short)f2b(v.z);
            t[cl + 3][kr] = (short)f2b(v.w);
        }
    }
    __syncthreads();
    {
        int ro = tid >> 2, co = (tid & 3) * 16;
        *(s16x8*)&out[(size_t)(n0 + ro) * R + k0 + co]     = *(s16x8*)&t[ro][co];
        *(s16x8*)&out[(size_t)(n0 + ro) * R + k0 + co + 8] = *(s16x8*)&t[ro][co + 8];
    }
}

// ---------------------------------------------------------------------------
// qkv_qk: Q,K columns (N=2048), bf16x3 (Ah*Bh + Ah*Bl + Al*Bh), hi/lo scatter.
// 128x128 tile, BK=32, unpadded LDS, global_load_lds staging.
// ---------------------------------------------------------------------------
__global__ __launch_bounds__(256) void qkv_qk(
    const short* __restrict__ Ah, const short* __restrict__ Al,
    const short* __restrict__ BTh, const short* __restrict__ BTl,
    const float* __restrict__ bias,
    short* __restrict__ Qh, short* __restrict__ Ql,
    short* __restrict__ Kh, short* __restrict__ Kl)
{
    __shared__ short Ash[128 * 32], Asl[128 * 32];
    __shared__ short Bsh[128 * 32], Bsl[128 * 32];

    const int tid  = threadIdx.x;
    const int wave = tid >> 6, lane = tid & 63;
    const int wm = wave >> 1, wn = wave & 1;
    const int lm = lane & 15, lq = lane >> 4;
    const int m0 = blockIdx.y * 128, n0 = blockIdx.x * 128;
    const int gr = (lane >> 2);             // row within 16-row segment
    const int gc = (lane & 3) * 8;          // col (shorts)

    f32x4 acc[4][4] = {};

    for (int k0 = 0; k0 < C_; k0 += 32) {
        __syncthreads();
        #pragma unroll
        for (int j = 0; j < 2; j++) {
            int s = wave * 2 + j;           // segment 0..7 (16 rows each)
            int row = s * 16 + gr;
            size_t ga = (size_t)(m0 + row) * C_ + k0 + gc;
            size_t gb = (size_t)(n0 + row) * C_ + k0 + gc;
            gload_lds16(&Ah[ga],  &Ash[s * 512]);
            gload_lds16(&Al[ga],  &Asl[s * 512]);
            gload_lds16(&BTh[gb], &Bsh[s * 512]);
            gload_lds16(&BTl[gb], &Bsl[s * 512]);
        }
        __syncthreads();

        s16x8 ah[4], al[4], bh[4], bl[4];
        #pragma unroll
        for (int mi = 0; mi < 4; mi++) {
            int r = wm * 64 + mi * 16 + lm;
            ah[mi] = *(const s16x8*)&Ash[r * 32 + lq * 8];
            al[mi] = *(const s16x8*)&Asl[r * 32 + lq * 8];
        }
        #pragma unroll
        for (int nj = 0; nj < 4; nj++) {
            int r = wn * 64 + nj * 16 + lm;
            bh[nj] = *(const s16x8*)&Bsh[r * 32 + lq * 8];
            bl[nj] = *(const s16x8*)&Bsl[r * 32 + lq * 8];
        }
        #pragma unroll
        for (int mi = 0; mi < 4; mi++)
            #pragma unroll
            for (int nj = 0; nj < 4; nj++) {
                acc[mi][nj] = __builtin_amdgcn_mfma_f32_16x16x32_bf16(
                    ah[mi], bh[nj], acc[mi][nj], 0, 0, 0);
                acc[mi][nj] = __builtin_amdgcn_mfma_f32_16x16x32_bf16(
                    ah[mi], bl[nj], acc[mi][nj], 0, 0, 0);
                acc[mi][nj] = __builtin_amdgcn_mfma_f32_16x16x32_bf16(
                    al[mi], bh[nj], acc[mi][nj], 0, 0, 0);
            }
    }

    #pragma unroll
    for (int nj = 0; nj < 4; nj++) {
        int n = n0 + wn * 64 + nj * 16 + lm;    // [0, 2048)
        float bv = bias[n];
        int isK = n >> 10;
        int c = n & (C_ - 1);
        int h = c >> 6, d = c & (D_ - 1);
        short* dh = isK ? Kh : Qh;
        short* dl = isK ? Kl : Ql;
        #pragma unroll
        for (int mi = 0; mi < 4; mi++) {
            #pragma unroll
            for (int r = 0; r < 4; r++) {
                int m  = m0 + wm * 64 + mi * 16 + lq * 4 + r;
                int bb = m >> 11, t = m & (T_ - 1);
                float v = acc[mi][nj][r] + bv;
                size_t idx = (((size_t)bb * H_ + h) * T_ + t) * D_ + d;
                unsigned short hb = f2b(v);
                dh[idx] = (short)hb;
                dl[idx] = (short)f2b(v - b2f(hb));
            }
        }
    }
}

// ---------------------------------------------------------------------------
// qkv_v: V columns (N=1024), single bf16, bf16 scatter.
// ---------------------------------------------------------------------------
__global__ __launch_bounds__(256) void qkv_v(
    const short* __restrict__ Ah, const short* __restrict__ BTh,
    const float* __restrict__ bias, short* __restrict__ Vb)
{
    __shared__ short Ash[128 * 32];
    __shared__ short Bsh[128 * 32];

    const int tid  = threadIdx.x;
    const int wave = tid >> 6, lane = tid & 63;
    const int wm = wave >> 1, wn = wave & 1;
    const int lm = lane & 15, lq = lane >> 4;
    const int m0 = blockIdx.y * 128, n0 = blockIdx.x * 128;
    const int gr = (lane >> 2);
    const int gc = (lane & 3) * 8;

    f32x4 acc[4][4] = {};

    for (int k0 = 0; k0 < C_; k0 += 32) {
        __syncthreads();
        #pragma unroll
        for (int j = 0; j < 2; j++) {
            int s = wave * 2 + j;
            int row = s * 16 + gr;
            gload_lds16(&Ah[(size_t)(m0 + row) * C_ + k0 + gc],  &Ash[s * 512]);
            gload_lds16(&BTh[(size_t)(n0 + row) * C_ + k0 + gc], &Bsh[s * 512]);
        }
        __syncthreads();

        s16x8 af[4], bfr[4];
        #pragma unroll
        for (int mi = 0; mi < 4; mi++)
            af[mi] = *(const s16x8*)&Ash[(wm * 64 + mi * 16 + lm) * 32 + lq * 8];
        #pragma unroll
        for (int nj = 0; nj < 4; nj++)
            bfr[nj] = *(const s16x8*)&Bsh[(wn * 64 + nj * 16 + lm) * 32 + lq * 8];
        #pragma unroll
        for (int mi = 0; mi < 4; mi++)
            #pragma unroll
            for (int nj = 0; nj < 4; nj++)
                acc[mi][nj] = __builtin_amdgcn_mfma_f32_16x16x32_bf16(
                    af[mi], bfr[nj], acc[mi][nj], 0, 0, 0);
    }

    #pragma unroll
    for (int nj = 0; nj < 4; nj++) {
        int n = n0 + wn * 64 + nj * 16 + lm;    // [0, 1024) local V channel
        float bv = bias[n];                      // bias pre-offset by caller
        int h = n >> 6, d = n & (D_ - 1);
        #pragma unroll
        for (int mi = 0; mi < 4; mi++) {
            #pragma unroll
            for (int r = 0; r < 4; r++) {
                int m  = m0 + wm * 64 + mi * 16 + lq * 4 + r;
                int bb = m >> 11, t = m & (T_ - 1);
                Vb[(((size_t)bb * H_ + h) * T_ + t) * D_ + d] =
                    (short)f2b(acc[mi][nj][r] + bv);
            }
        }
    }
}

// ---------------------------------------------------------------------------
// proj: out fp32 [M,C] = Yb(bf16) @ WpT(bf16) + bias, global_load_lds staging.
// ---------------------------------------------------------------------------
__global__ __launch_bounds__(256) void proj_mfma(
    const short* __restrict__ A, const short* __restrict__ BT,
    const float* __restrict__ bias, float* __restrict__ out)
{
    __shared__ short Ash[128 * 32];
    __shared__ short Bsh[128 * 32];

    const int tid  = threadIdx.x;
    const int wave = tid >> 6, lane = tid & 63;
    const int wm = wave >> 1, wn = wave & 1;
    const int lm = lane & 15, lq = lane >> 4;
    const int m0 = blockIdx.y * 128, n0 = blockIdx.x * 128;
    const int gr = (lane >> 2);
    const int gc = (lane & 3) * 8;

    f32x4 acc[4][4] = {};

    for (int k0 = 0; k0 < C_; k0 += 32) {
        __syncthreads();
        #pragma unroll
        for (int j = 0; j < 2; j++) {
            int s = wave * 2 + j;
            int row = s * 16 + gr;
            gload_lds16(&A[(size_t)(m0 + row) * C_ + k0 + gc],  &Ash[s * 512]);
            gload_lds16(&BT[(size_t)(n0 + row) * C_ + k0 + gc], &Bsh[s * 512]);
        }
        __syncthreads();

        s16x8 af[4], bfr[4];
        #pragma unroll
        for (int mi = 0; mi < 4; mi++)
            af[mi] = *(const s16x8*)&Ash[(wm * 64 + mi * 16 + lm) * 32 + lq * 8];
        #pragma unroll
        for (int nj = 0; nj < 4; nj++)
            bfr[nj] = *(const s16x8*)&Bsh[(wn * 64 + nj * 16 + lm) * 32 + lq * 8];
        #pragma unroll
        for (int mi = 0; mi < 4; mi++)
            #pragma unroll
            for (int nj = 0; nj < 4; nj++)
                acc[mi][nj] = __builtin_amdgcn_mfma_f32_16x16x32_bf16(
                    af[mi], bfr[nj], acc[mi][nj], 0, 0, 0);
    }

    #pragma unroll
    for (int nj = 0; nj < 4; nj++) {
        int n = n0 + wn * 64 + nj * 16 + lm;
        float bv = bias[n];
        #pragma unroll
        for (int mi = 0; mi < 4; mi++) {
            #pragma unroll
            for (int r = 0; r < 4; r++) {
                int m = m0 + wm * 64 + mi * 16 + lq * 4 + r;
                out[(size_t)m * C_ + n] = acc[mi][nj][r] + bv;
            }
        }
    }
}

// ---------------------------------------------------------------------------
// MFMA flash attention (unchanged from round 8).
// ---------------------------------------------------------------------------
__global__ __launch_bounds__(256) void attn_mfma(
    const short* __restrict__ Qh, const short* __restrict__ Ql,
    const short* __restrict__ Kh, const short* __restrict__ Kl,
    const short* __restrict__ V,  short* __restrict__ Yb)
{
    __shared__ short Qsh[64][72], Qsl[64][72];   // [q][d]
    __shared__ short Ksh[64][72], Ksl[64][72];   // [key][d]
    __shared__ short Vt [64][72];                // [d][key]
    __shared__ short Ps [4][16][72];             // per-wave P [qrow][key]

    const int tid  = threadIdx.x;
    const int wave = tid >> 6, lane = tid & 63;
    const int lm   = lane & 15, quad = lane >> 4;
    const int bh   = blockIdx.y;
    const int b    = bh >> 4, h = bh & (H_ - 1);
    const size_t base = (size_t)bh * T_ * D_;

    for (int half = 0; half < 2; half++) {
        const int qt = (half == 0) ? blockIdx.x : 31 - blockIdx.x;
        const int q0 = qt * 64;

        __syncthreads();
        #pragma unroll
        for (int i = 0; i < 2; i++) {
            int c = i * 256 + tid;
            int row = c >> 3, ch = (c & 7) * 8;
            size_t g = base + (size_t)(q0 + row) * D_ + ch;
            *(s16x8*)&Qsh[row][ch] = *(const s16x8*)&Qh[g];
            *(s16x8*)&Qsl[row][ch] = *(const s16x8*)&Ql[g];
        }
        __syncthreads();

        s16x8 aqh[2], aql[2];
        #pragma unroll
        for (int kc = 0; kc < 2; kc++) {
            aqh[kc] = *(const s16x8*)&Qsh[wave * 16 + lm][kc * 32 + quad * 8];
            aql[kc] = *(const s16x8*)&Qsl[wave * 16 + lm][kc * 32 + quad * 8];
        }

        float mrow[4], lrow[4];
        f32x4 O[4] = {};
        #pragma unroll
        for (int r = 0; r < 4; r++) { mrow[r] = -INFINITY; lrow[r] = 0.f; }

        for (int kt = 0; kt <= qt; kt++) {
            __syncthreads();
            #pragma unroll
            for (int i = 0; i < 2; i++) {
                int c = i * 256 + tid;
                int row = c >> 3, ch = (c & 7) * 8;
                size_t g = base + (size_t)(kt * 64 + row) * D_ + ch;
                *(s16x8*)&Ksh[row][ch] = *(const s16x8*)&Kh[g];
                *(s16x8*)&Ksl[row][ch] = *(const s16x8*)&Kl[g];
            }
            #pragma unroll
            for (int i = 0; i < 2; i++) {
                int c = i * 256 + tid;
                int dc = c & 7, key = c >> 3;
                s16x8 v8 = *(const s16x8*)&V[base + (size_t)(kt * 64 + key) * D_ + dc * 8];
                #pragma unroll
                for (int j = 0; j < 8; j++) {
                    int e = (j + dc) & 7;
                    Vt[dc * 8 + e][key] = v8[e];
                }
            }
            __syncthreads();

            f32x4 S[4] = {};
            #pragma unroll
            for (int t = 0; t < 4; t++) {
                #pragma unroll
                for (int kc = 0; kc < 2; kc++) {
                    s16x8 kh8 = *(const s16x8*)&Ksh[t * 16 + lm][kc * 32 + quad * 8];
                    s16x8 kl8 = *(const s16x8*)&Ksl[t * 16 + lm][kc * 32 + quad * 8];
                    S[t] = __builtin_amdgcn_mfma_f32_16x16x32_bf16(aqh[kc], kh8, S[t], 0, 0, 0);
                    S[t] = __builtin_amdgcn_mfma_f32_16x16x32_bf16(aqh[kc], kl8, S[t], 0, 0, 0);
                    S[t] = __builtin_amdgcn_mfma_f32_16x16x32_bf16(aql[kc], kh8, S[t], 0, 0, 0);
                }
            }

            #pragma unroll
            for (int t = 0; t < 4; t++)
                #pragma unroll
                for (int r = 0; r < 4; r++) {
                    float v = S[t][r] * 8.0f;
                    if (kt == qt && (t * 16 + lm) > (wave * 16 + quad * 4 + r))
                        v = -INFINITY;
                    S[t][r] = v;
                }

            float alpha[4];
            #pragma unroll
            for (int r = 0; r < 4; r++) {
                float rm = fmaxf(fmaxf(S[0][r], S[1][r]), fmaxf(S[2][r], S[3][r]));
                #pragma unroll
                for (int off = 1; off < 16; off <<= 1)
                    rm = fmaxf(rm, __shfl_xor(rm, off, 64));
                float mnew = fmaxf(mrow[r], rm);
                alpha[r] = __expf(mrow[r] - mnew);
                mrow[r] = mnew;
                float rs = 0.f;
                #pragma unroll
                for (int t = 0; t < 4; t++) {
                    S[t][r] = __expf(S[t][r] - mnew);
                    rs += S[t][r];
                }
                #pragma unroll
                for (int off = 1; off < 16; off <<= 1)
                    rs += __shfl_xor(rs, off, 64);
                lrow[r] = lrow[r] * alpha[r] + rs;
            }
            #pragma unroll
            for (int t = 0; t < 4; t++)
                #pragma unroll
                for (int r = 0; r < 4; r++) O[t][r] *= alpha[r];

            #pragma unroll
            for (int t = 0; t < 4; t++)
                #pragma unroll
                for (int r = 0; r < 4; r++)
                    Ps[wave][quad * 4 + r][t * 16 + lm] = (short)f2b(S[t][r]);

            s16x8 ap[2];
            #pragma unroll
            for (int kc = 0; kc < 2; kc++)
                ap[kc] = *(const s16x8*)&Ps[wave][lm][kc * 32 + quad * 8];
            #pragma unroll
            for (int t = 0; t < 4; t++) {
                #pragma unroll
                for (int kc = 0; kc < 2; kc++) {
                    s16x8 bv = *(const s16x8*)&Vt[t * 16 + lm][kc * 32 + quad * 8];
                    O[t] = __builtin_amdgcn_mfma_f32_16x16x32_bf16(ap[kc], bv, O[t], 0, 0, 0);
                }
            }
        }

        #pragma unroll
        for (int t = 0; t < 4; t++)
            #pragma unroll
            for (int r = 0; r < 4; r++) {
                int q = q0 + wave * 16 + quad * 4 + r;
                int d = t * 16 + lm;
                Yb[((size_t)b * T_ + q) * C_ + h * D_ + d] =
                    (short)f2b(O[t][r] / lrow[r]);
            }
    }
}

// ---------------------------------------------------------------------------
extern "C" void kernel_launch(void* const* d_in, const int* in_sizes, int n_in,
                              void* d_out, int out_size, void* d_ws, size_t ws_size,
                              hipStream_t stream)
{
    const float* x      = (const float*)d_in[0];
    const float* W_attn = (const float*)d_in[1];
    const float* b_attn = (const float*)d_in[2];
    const float* W_proj = (const float*)d_in[3];
    const float* b_proj = (const float*)d_in[4];
    float* out = (float*)d_out;

    char* ws = (char*)d_ws;
    const size_t MB = 1024 * 1024;
    short* Qh   = (short*)(ws);            // 8 MB  [ 0, 8)
    short* Ql   = (short*)(ws +  8 * MB);  // 8 MB  [ 8,16)
    short* Kh   = (short*)(ws + 16 * MB);  // 8 MB  [16,24)
    short* Kl   = (short*)(ws + 24 * MB);  // 8 MB  [24,32)
    short* xh   = (short*)(ws + 32 * MB);  // 8 MB  [32,40)  dead after qkv_v
    short* xl   = (short*)(ws + 40 * MB);  // 8 MB  [40,48)  dead after qkv_qk
    short* WaTh = (short*)(ws + 48 * MB);  // 6 MB  [48,54)  [3072,1024]
    short* WaTl = (short*)(ws + 54 * MB);  // 6 MB  [54,60)
    short* WpT  = (short*)(ws + 60 * MB);  // 2 MB  [60,62)
    short* Vb   = (short*)(ws + 40 * MB);  // 8 MB  aliases xl (born at qkv_v)
    short* Yb   = (short*)(ws + 32 * MB);  // 8 MB  aliases xh (born at attn)

    cvt_split <<<dim3(M_ * C_ / 2048), 256, 0, stream>>>(x, xh, xl, M_ * C_);
    cvtT_split<<<dim3(N3_ / 64, C_ / 64), 256, 0, stream>>>(W_attn, WaTh, WaTl, C_, N3_);
    cvtT_bf16 <<<dim3(C_ / 64, C_ / 64), 256, 0, stream>>>(W_proj, WpT, C_, C_);

    qkv_qk <<<dim3(16, 32), 256, 0, stream>>>(xh, xl, WaTh, WaTl, b_attn,
                                              Qh, Ql, Kh, Kl);
    qkv_v  <<<dim3(8, 32), 256, 0, stream>>>(xh, WaTh + (size_t)2048 * C_,
                                             b_attn + 2048, Vb);
    attn_mfma<<<dim3(16, 32), 256, 0, stream>>>(Qh, Ql, Kh, Kl, Vb, Yb);
    proj_mfma<<<dim3(8, 32), 256, 0, stream>>>(Yb, WpT, b_proj, out);
}

// Round 10
// 265.320 us; speedup vs baseline: 20.1271x; 1.1368x over previous
//
#include <hip/hip_runtime.h>
#include <hip/hip_bf16.h>

// Problem: CausalSelfAttention  B=2, T=2048, C=1024, H=16, D=64
// Round 10: attention layout rework. S^T MFMA (A=K, B=Q) -> softmax rows at
// q=lane&15: 2-step shfl reductions, 1 exp alpha; P^T written as b64; V kept
// transposed in GLOBAL ([B,H,D,T], free in qkv_v scatter) -> Vt staged with
// b128 writes. S path stays bf16x3. GEMMs unchanged from r9.
// ws (62 MB): Qh 8|Ql 8|Kh 8|Kl 8|xh 8(->Yb)|xl 8(->VT)|WaTh 6|WaTl 6|WpT 2

#define B_  2
#define T_  2048
#define C_  1024
#define H_  16
#define D_  64
#define M_  (B_ * T_)      // 4096
#define N3_ (3 * C_)       // 3072

typedef __attribute__((ext_vector_type(8))) short s16x8;
typedef __attribute__((ext_vector_type(4))) short s16x4;
typedef __attribute__((ext_vector_type(4))) float f32x4;

typedef const __attribute__((address_space(1))) unsigned int gu32_t;
typedef __attribute__((address_space(3))) unsigned int lu32_t;

__device__ __forceinline__ void gload_lds16(const short* g, short* l) {
    __builtin_amdgcn_global_load_lds((gu32_t*)g, (lu32_t*)l, 16, 0, 0);
}

__device__ __forceinline__ float b2f(unsigned short u) {
    return __uint_as_float(((unsigned)u) << 16);
}
__device__ __forceinline__ unsigned short f2b(float f) {   // RNE bf16 round
    unsigned u = __float_as_uint(f);
    return (unsigned short)((u + 0x7FFFu + ((u >> 16) & 1u)) >> 16);
}

// ---------------------------------------------------------------------------
// fp32 -> (hi, lo) bf16 split. n multiple of 2048.
// ---------------------------------------------------------------------------
__global__ __launch_bounds__(256) void cvt_split(
    const float* __restrict__ in, short* __restrict__ oh, short* __restrict__ ol, int n)
{
    int i = (blockIdx.x * 256 + threadIdx.x) * 8;
    if (i >= n) return;
    float4 a = *(const float4*)&in[i];
    float4 b = *(const float4*)&in[i + 4];
    float v[8] = {a.x, a.y, a.z, a.w, b.x, b.y, b.z, b.w};
    s16x8 h, l;
    #pragma unroll
    for (int j = 0; j < 8; j++) {
        unsigned short hb = f2b(v[j]);
        h[j] = (short)hb;
        l[j] = (short)f2b(v[j] - b2f(hb));
    }
    *(s16x8*)&oh[i] = h;
    *(s16x8*)&ol[i] = l;
}

// ---------------------------------------------------------------------------
// fp32 [R,Cn] -> (hi,lo) bf16 [Cn,R] transpose+split. grid (Cn/64, R/64).
// ---------------------------------------------------------------------------
__global__ __launch_bounds__(256) void cvtT_split(
    const float* __restrict__ in, short* __restrict__ oh, short* __restrict__ ol,
    int R, int Cn)
{
    __shared__ short th[64][80];
    __shared__ short tl[64][80];
    const int tid = threadIdx.x;
    const int k0 = blockIdx.y * 64;
    const int n0 = blockIdx.x * 64;
    {
        int rl = tid >> 4, cl = (tid & 15) * 4;
        #pragma unroll
        for (int i = 0; i < 4; i++) {
            int kr = rl + i * 16;
            float4 v4 = *(const float4*)&in[(size_t)(k0 + kr) * Cn + n0 + cl];
            float v[4] = {v4.x, v4.y, v4.z, v4.w};
            #pragma unroll
            for (int j = 0; j < 4; j++) {
                unsigned short hb = f2b(v[j]);
                th[cl + j][kr] = (short)hb;
                tl[cl + j][kr] = (short)f2b(v[j] - b2f(hb));
            }
        }
    }
    __syncthreads();
    {
        int ro = tid >> 2, co = (tid & 3) * 16;
        *(s16x8*)&oh[(size_t)(n0 + ro) * R + k0 + co]     = *(s16x8*)&th[ro][co];
        *(s16x8*)&oh[(size_t)(n0 + ro) * R + k0 + co + 8] = *(s16x8*)&th[ro][co + 8];
        *(s16x8*)&ol[(size_t)(n0 + ro) * R + k0 + co]     = *(s16x8*)&tl[ro][co];
        *(s16x8*)&ol[(size_t)(n0 + ro) * R + k0 + co + 8] = *(s16x8*)&tl[ro][co + 8];
    }
}

// ---------------------------------------------------------------------------
// fp32 [R,Cn] -> bf16 [Cn,R] transpose (single, for W_proj).
// ---------------------------------------------------------------------------
__global__ __launch_bounds__(256) void cvtT_bf16(
    const float* __restrict__ in, short* __restrict__ out, int R, int Cn)
{
    __shared__ short t[64][80];
    const int tid = threadIdx.x;
    const int k0 = blockIdx.y * 64;
    const int n0 = blockIdx.x * 64;
    {
        int rl = tid >> 4, cl = (tid & 15) * 4;
        #pragma unroll
        for (int i = 0; i < 4; i++) {
            int kr = rl + i * 16;
            float4 v = *(const float4*)&in[(size_t)(k0 + kr) * Cn + n0 + cl];
            t[cl + 0][kr] = (short)f2b(v.x);
            t[cl + 1][kr] = (short)f2b(v.y);
            t[cl + 2][kr] = (short)f2b(v.z);
            t[cl + 3][kr] = (short)f2b(v.w);
        }
    }
    __syncthreads();
    {
        int ro = tid >> 2, co = (tid & 3) * 16;
        *(s16x8*)&out[(size_t)(n0 + ro) * R + k0 + co]     = *(s16x8*)&t[ro][co];
        *(s16x8*)&out[(size_t)(n0 + ro) * R + k0 + co + 8] = *(s16x8*)&t[ro][co + 8];
    }
}

// ---------------------------------------------------------------------------
// qkv_qk: Q,K columns (N=2048), bf16x3, hi/lo scatter. (unchanged from r9)
// ---------------------------------------------------------------------------
__global__ __launch_bounds__(256) void qkv_qk(
    const short* __restrict__ Ah, const short* __restrict__ Al,
    const short* __restrict__ BTh, const short* __restrict__ BTl,
    const float* __restrict__ bias,
    short* __restrict__ Qh, short* __restrict__ Ql,
    short* __restrict__ Kh, short* __restrict__ Kl)
{
    __shared__ short Ash[128 * 32], Asl[128 * 32];
    __shared__ short Bsh[128 * 32], Bsl[128 * 32];

    const int tid  = threadIdx.x;
    const int wave = tid >> 6, lane = tid & 63;
    const int wm = wave >> 1, wn = wave & 1;
    const int lm = lane & 15, lq = lane >> 4;
    const int m0 = blockIdx.y * 128, n0 = blockIdx.x * 128;
    const int gr = (lane >> 2);
    const int gc = (lane & 3) * 8;

    f32x4 acc[4][4] = {};

    for (int k0 = 0; k0 < C_; k0 += 32) {
        __syncthreads();
        #pragma unroll
        for (int j = 0; j < 2; j++) {
            int s = wave * 2 + j;
            int row = s * 16 + gr;
            size_t ga = (size_t)(m0 + row) * C_ + k0 + gc;
            size_t gb = (size_t)(n0 + row) * C_ + k0 + gc;
            gload_lds16(&Ah[ga],  &Ash[s * 512]);
            gload_lds16(&Al[ga],  &Asl[s * 512]);
            gload_lds16(&BTh[gb], &Bsh[s * 512]);
            gload_lds16(&BTl[gb], &Bsl[s * 512]);
        }
        __syncthreads();

        s16x8 ah[4], al[4], bh[4], bl[4];
        #pragma unroll
        for (int mi = 0; mi < 4; mi++) {
            int r = wm * 64 + mi * 16 + lm;
            ah[mi] = *(const s16x8*)&Ash[r * 32 + lq * 8];
            al[mi] = *(const s16x8*)&Asl[r * 32 + lq * 8];
        }
        #pragma unroll
        for (int nj = 0; nj < 4; nj++) {
            int r = wn * 64 + nj * 16 + lm;
            bh[nj] = *(const s16x8*)&Bsh[r * 32 + lq * 8];
            bl[nj] = *(const s16x8*)&Bsl[r * 32 + lq * 8];
        }
        #pragma unroll
        for (int mi = 0; mi < 4; mi++)
            #pragma unroll
            for (int nj = 0; nj < 4; nj++) {
                acc[mi][nj] = __builtin_amdgcn_mfma_f32_16x16x32_bf16(
                    ah[mi], bh[nj], acc[mi][nj], 0, 0, 0);
                acc[mi][nj] = __builtin_amdgcn_mfma_f32_16x16x32_bf16(
                    ah[mi], bl[nj], acc[mi][nj], 0, 0, 0);
                acc[mi][nj] = __builtin_amdgcn_mfma_f32_16x16x32_bf16(
                    al[mi], bh[nj], acc[mi][nj], 0, 0, 0);
            }
    }

    #pragma unroll
    for (int nj = 0; nj < 4; nj++) {
        int n = n0 + wn * 64 + nj * 16 + lm;
        float bv = bias[n];
        int isK = n >> 10;
        int c = n & (C_ - 1);
        int h = c >> 6, d = c & (D_ - 1);
        short* dh = isK ? Kh : Qh;
        short* dl = isK ? Kl : Ql;
        #pragma unroll
        for (int mi = 0; mi < 4; mi++) {
            #pragma unroll
            for (int r = 0; r < 4; r++) {
                int m  = m0 + wm * 64 + mi * 16 + lq * 4 + r;
                int bb = m >> 11, t = m & (T_ - 1);
                float v = acc[mi][nj][r] + bv;
                size_t idx = (((size_t)bb * H_ + h) * T_ + t) * D_ + d;
                unsigned short hb = f2b(v);
                dh[idx] = (short)hb;
                dl[idx] = (short)f2b(v - b2f(hb));
            }
        }
    }
}

// ---------------------------------------------------------------------------
// qkv_v: V columns (N=1024), single bf16, scatter TRANSPOSED -> VT [B,H,D,T].
// ---------------------------------------------------------------------------
__global__ __launch_bounds__(256) void qkv_v(
    const short* __restrict__ Ah, const short* __restrict__ BTh,
    const float* __restrict__ bias, short* __restrict__ VT)
{
    __shared__ short Ash[128 * 32];
    __shared__ short Bsh[128 * 32];

    const int tid  = threadIdx.x;
    const int wave = tid >> 6, lane = tid & 63;
    const int wm = wave >> 1, wn = wave & 1;
    const int lm = lane & 15, lq = lane >> 4;
    const int m0 = blockIdx.y * 128, n0 = blockIdx.x * 128;
    const int gr = (lane >> 2);
    const int gc = (lane & 3) * 8;

    f32x4 acc[4][4] = {};

    for (int k0 = 0; k0 < C_; k0 += 32) {
        __syncthreads();
        #pragma unroll
        for (int j = 0; j < 2; j++) {
            int s = wave * 2 + j;
            int row = s * 16 + gr;
            gload_lds16(&Ah[(size_t)(m0 + row) * C_ + k0 + gc],  &Ash[s * 512]);
            gload_lds16(&BTh[(size_t)(n0 + row) * C_ + k0 + gc], &Bsh[s * 512]);
        }
        __syncthreads();

        s16x8 af[4], bfr[4];
        #pragma unroll
        for (int mi = 0; mi < 4; mi++)
            af[mi] = *(const s16x8*)&Ash[(wm * 64 + mi * 16 + lm) * 32 + lq * 8];
        #pragma unroll
        for (int nj = 0; nj < 4; nj++)
            bfr[nj] = *(const s16x8*)&Bsh[(wn * 64 + nj * 16 + lm) * 32 + lq * 8];
        #pragma unroll
        for (int mi = 0; mi < 4; mi++)
            #pragma unroll
            for (int nj = 0; nj < 4; nj++)
                acc[mi][nj] = __builtin_amdgcn_mfma_f32_16x16x32_bf16(
                    af[mi], bfr[nj], acc[mi][nj], 0, 0, 0);
    }

    #pragma unroll
    for (int nj = 0; nj < 4; nj++) {
        int n = n0 + wn * 64 + nj * 16 + lm;    // [0, 1024) V channel
        float bv = bias[n];
        int h = n >> 6, d = n & (D_ - 1);
        #pragma unroll
        for (int mi = 0; mi < 4; mi++) {
            #pragma unroll
            for (int r = 0; r < 4; r++) {
                int m  = m0 + wm * 64 + mi * 16 + lq * 4 + r;
                int bb = m >> 11, t = m & (T_ - 1);
                VT[(((size_t)bb * H_ + h) * D_ + d) * T_ + t] =
                    (short)f2b(acc[mi][nj][r] + bv);
            }
        }
    }
}

// ---------------------------------------------------------------------------
// proj: out fp32 [M,C] = Yb(bf16) @ WpT(bf16) + bias. (unchanged from r9)
// ---------------------------------------------------------------------------
__global__ __launch_bounds__(256) void proj_mfma(
    const short* __restrict__ A, const short* __restrict__ BT,
    const float* __restrict__ bias, float* __restrict__ out)
{
    __shared__ short Ash[128 * 32];
    __shared__ short Bsh[128 * 32];

    const int tid  = threadIdx.x;
    const int wave = tid >> 6, lane = tid & 63;
    const int wm = wave >> 1, wn = wave & 1;
    const int lm = lane & 15, lq = lane >> 4;
    const int m0 = blockIdx.y * 128, n0 = blockIdx.x * 128;
    const int gr = (lane >> 2);
    const int gc = (lane & 3) * 8;

    f32x4 acc[4][4] = {};

    for (int k0 = 0; k0 < C_; k0 += 32) {
        __syncthreads();
        #pragma unroll
        for (int j = 0; j < 2; j++) {
            int s = wave * 2 + j;
            int row = s * 16 + gr;
            gload_lds16(&A[(size_t)(m0 + row) * C_ + k0 + gc],  &Ash[s * 512]);
            gload_lds16(&BT[(size_t)(n0 + row) * C_ + k0 + gc], &Bsh[s * 512]);
        }
        __syncthreads();

        s16x8 af[4], bfr[4];
        #pragma unroll
        for (int mi = 0; mi < 4; mi++)
            af[mi] = *(const s16x8*)&Ash[(wm * 64 + mi * 16 + lm) * 32 + lq * 8];
        #pragma unroll
        for (int nj = 0; nj < 4; nj++)
            bfr[nj] = *(const s16x8*)&Bsh[(wn * 64 + nj * 16 + lm) * 32 + lq * 8];
        #pragma unroll
        for (int mi = 0; mi < 4; mi++)
            #pragma unroll
            for (int nj = 0; nj < 4; nj++)
                acc[mi][nj] = __builtin_amdgcn_mfma_f32_16x16x32_bf16(
                    af[mi], bfr[nj], acc[mi][nj], 0, 0, 0);
    }

    #pragma unroll
    for (int nj = 0; nj < 4; nj++) {
        int n = n0 + wn * 64 + nj * 16 + lm;
        float bv = bias[n];
        #pragma unroll
        for (int mi = 0; mi < 4; mi++) {
            #pragma unroll
            for (int r = 0; r < 4; r++) {
                int m = m0 + wm * 64 + mi * 16 + lq * 4 + r;
                out[(size_t)m * C_ + n] = acc[mi][nj][r] + bv;
            }
        }
    }
}

// ---------------------------------------------------------------------------
// MFMA flash attention, S^T layout.
// Wave w owns q = q0 + w*16 + lm (B-operand). S^T = K@Q^T: C col=lm=q,
// row=quad*4+r (+16t) = key. Softmax per-thread (one q), 2-shfl reductions.
// P^T -> Ps[q][key] b64 writes; PV: A=P (m=q), B=Vt (n=d) -> O col=d,row=q.
// Faithful scale: S = (q.k) * 8.
// ---------------------------------------------------------------------------
__global__ __launch_bounds__(256) void attn_mfma(
    const short* __restrict__ Qh, const short* __restrict__ Ql,
    const short* __restrict__ Kh, const short* __restrict__ Kl,
    const short* __restrict__ VT, short* __restrict__ Yb)
{
    __shared__ short Qsh[64][72], Qsl[64][72];   // [q][d]
    __shared__ short Ksh[64][72], Ksl[64][72];   // [key][d]
    __shared__ short Vt [64][72];                // [d][key]
    __shared__ short Ps [4][16][72];             // per-wave P [q][key]

    const int tid  = threadIdx.x;
    const int wave = tid >> 6, lane = tid & 63;
    const int lm   = lane & 15, quad = lane >> 4;
    const int bh   = blockIdx.y;
    const int b    = bh >> 4, h = bh & (H_ - 1);
    const size_t base = (size_t)bh * T_ * D_;    // Q,K: [b,h,t,d]
    const size_t vbase = (size_t)bh * D_ * T_;   // VT:  [b,h,d,t]

    for (int half = 0; half < 2; half++) {
        const int qt = (half == 0) ? blockIdx.x : 31 - blockIdx.x;
        const int q0 = qt * 64;

        __syncthreads();
        #pragma unroll
        for (int i = 0; i < 2; i++) {      // stage Q hi/lo (64 q x 64 d)
            int c = i * 256 + tid;
            int row = c >> 3, ch = (c & 7) * 8;
            size_t g = base + (size_t)(q0 + row) * D_ + ch;
            *(s16x8*)&Qsh[row][ch] = *(const s16x8*)&Qh[g];
            *(s16x8*)&Qsl[row][ch] = *(const s16x8*)&Ql[g];
        }
        __syncthreads();

        // hoist Q B-frags: B[n=q=lm][k=d chunk]
        s16x8 bqh[2], bql[2];
        #pragma unroll
        for (int kc = 0; kc < 2; kc++) {
            bqh[kc] = *(const s16x8*)&Qsh[wave * 16 + lm][kc * 32 + quad * 8];
            bql[kc] = *(const s16x8*)&Qsl[wave * 16 + lm][kc * 32 + quad * 8];
        }

        float mrow = -INFINITY, lrow = 0.f;
        f32x4 O[4] = {};

        for (int kt = 0; kt <= qt; kt++) {
            __syncthreads();
            #pragma unroll
            for (int i = 0; i < 2; i++) {  // stage K hi/lo
                int c = i * 256 + tid;
                int row = c >> 3, ch = (c & 7) * 8;
                size_t g = base + (size_t)(kt * 64 + row) * D_ + ch;
                *(s16x8*)&Ksh[row][ch] = *(const s16x8*)&Kh[g];
                *(s16x8*)&Ksl[row][ch] = *(const s16x8*)&Kl[g];
            }
            #pragma unroll
            for (int i = 0; i < 2; i++) {  // stage Vt from transposed global
                int c = i * 256 + tid;
                int d = c >> 3, ch = (c & 7) * 8;
                *(s16x8*)&Vt[d][ch] =
                    *(const s16x8*)&VT[vbase + (size_t)d * T_ + kt * 64 + ch];
            }
            __syncthreads();

            // ---- S^T = K Q^T (bf16x3): A=K (m=key), B=Q (n=q) ----
            f32x4 S[4] = {};
            #pragma unroll
            for (int t = 0; t < 4; t++) {
                #pragma unroll
                for (int kc = 0; kc < 2; kc++) {
                    s16x8 kh8 = *(const s16x8*)&Ksh[t * 16 + lm][kc * 32 + quad * 8];
                    s16x8 kl8 = *(const s16x8*)&Ksl[t * 16 + lm][kc * 32 + quad * 8];
                    S[t] = __builtin_amdgcn_mfma_f32_16x16x32_bf16(kh8, bqh[kc], S[t], 0, 0, 0);
                    S[t] = __builtin_amdgcn_mfma_f32_16x16x32_bf16(kl8, bqh[kc], S[t], 0, 0, 0);
                    S[t] = __builtin_amdgcn_mfma_f32_16x16x32_bf16(kh8, bql[kc], S[t], 0, 0, 0);
                }
            }

            // scale + causal mask: key = t*16+quad*4+r, q = wave*16+lm
            const int qg = wave * 16 + lm;
            #pragma unroll
            for (int t = 0; t < 4; t++)
                #pragma unroll
                for (int r = 0; r < 4; r++) {
                    float v = S[t][r] * 8.0f;
                    if (kt == qt && (t * 16 + quad * 4 + r) > qg) v = -INFINITY;
                    S[t][r] = v;
                }

            // ---- online softmax, one q per thread (replicated x4 quads) ----
            float rm = -INFINITY;
            #pragma unroll
            for (int t = 0; t < 4; t++)
                #pragma unroll
                for (int r = 0; r < 4; r++) rm = fmaxf(rm, S[t][r]);
            rm = fmaxf(rm, __shfl_xor(rm, 16, 64));
            rm = fmaxf(rm, __shfl_xor(rm, 32, 64));
            float mnew  = fmaxf(mrow, rm);
            float alpha = __expf(mrow - mnew);
            mrow = mnew;
            float rs = 0.f;
            #pragma unroll
            for (int t = 0; t < 4; t++)
                #pragma unroll
                for (int r = 0; r < 4; r++) {
                    S[t][r] = __expf(S[t][r] - mnew);
                    rs += S[t][r];
                }
            rs += __shfl_xor(rs, 16, 64);
            rs += __shfl_xor(rs, 32, 64);
            lrow = lrow * alpha + rs;

            // broadcast alpha to O-row layout (O row q = quad*4+r)
            float al[4];
            #pragma unroll
            for (int r = 0; r < 4; r++) al[r] = __shfl(alpha, quad * 4 + r, 64);
            #pragma unroll
            for (int t = 0; t < 4; t++)
                #pragma unroll
                for (int r = 0; r < 4; r++) O[t][r] *= al[r];

            // ---- P^T -> Ps[q][key], 4 contiguous keys per b64 write ----
            #pragma unroll
            for (int t = 0; t < 4; t++) {
                s16x4 p;
                #pragma unroll
                for (int r = 0; r < 4; r++) p[r] = (short)f2b(S[t][r]);
                *(s16x4*)&Ps[wave][lm][t * 16 + quad * 4] = p;
            }
            // wave-private slab: no barrier (lgkmcnt ordering within wave)

            // ---- O += P V: A=P (m=q), B=Vt (n=d) ----
            s16x8 ap[2];
            #pragma unroll
            for (int kc = 0; kc < 2; kc++)
                ap[kc] = *(const s16x8*)&Ps[wave][lm][kc * 32 + quad * 8];
            #pragma unroll
            for (int t = 0; t < 4; t++) {
                #pragma unroll
                for (int kc = 0; kc < 2; kc++) {
                    s16x8 bv = *(const s16x8*)&Vt[t * 16 + lm][kc * 32 + quad * 8];
                    O[t] = __builtin_amdgcn_mfma_f32_16x16x32_bf16(ap[kc], bv, O[t], 0, 0, 0);
                }
            }
        }

        // ---- epilogue: O row q = wave*16+quad*4+r, col d = t*16+lm ----
        float li[4];
        #pragma unroll
        for (int r = 0; r < 4; r++)
            li[r] = 1.0f / __shfl(lrow, quad * 4 + r, 64);
        #pragma unroll
        for (int t = 0; t < 4; t++)
            #pragma unroll
            for (int r = 0; r < 4; r++) {
                int q = q0 + wave * 16 + quad * 4 + r;
                int d = t * 16 + lm;
                Yb[((size_t)b * T_ + q) * C_ + h * D_ + d] =
                    (short)f2b(O[t][r] * li[r]);
            }
    }
}

// ---------------------------------------------------------------------------
extern "C" void kernel_launch(void* const* d_in, const int* in_sizes, int n_in,
                              void* d_out, int out_size, void* d_ws, size_t ws_size,
                              hipStream_t stream)
{
    const float* x      = (const float*)d_in[0];
    const float* W_attn = (const float*)d_in[1];
    const float* b_attn = (const float*)d_in[2];
    const float* W_proj = (const float*)d_in[3];
    const float* b_proj = (const float*)d_in[4];
    float* out = (float*)d_out;

    char* ws = (char*)d_ws;
    const size_t MB = 1024 * 1024;
    short* Qh   = (short*)(ws);            // 8 MB  [ 0, 8)
    short* Ql   = (short*)(ws +  8 * MB);  // 8 MB  [ 8,16)
    short* Kh   = (short*)(ws + 16 * MB);  // 8 MB  [16,24)
    short* Kl   = (short*)(ws + 24 * MB);  // 8 MB  [24,32)
    short* xh   = (short*)(ws + 32 * MB);  // 8 MB  [32,40)  dead after qkv_v
    short* xl   = (short*)(ws + 40 * MB);  // 8 MB  [40,48)  dead after qkv_qk
    short* WaTh = (short*)(ws + 48 * MB);  // 6 MB  [48,54)
    short* WaTl = (short*)(ws + 54 * MB);  // 6 MB  [54,60)
    short* WpT  = (short*)(ws + 60 * MB);  // 2 MB  [60,62)
    short* VT   = (short*)(ws + 40 * MB);  // 8 MB  aliases xl (born at qkv_v)
    short* Yb   = (short*)(ws + 32 * MB);  // 8 MB  aliases xh (born at attn)

    cvt_split <<<dim3(M_ * C_ / 2048), 256, 0, stream>>>(x, xh, xl, M_ * C_);
    cvtT_split<<<dim3(N3_ / 64, C_ / 64), 256, 0, stream>>>(W_attn, WaTh, WaTl, C_, N3_);
    cvtT_bf16 <<<dim3(C_ / 64, C_ / 64), 256, 0, stream>>>(W_proj, WpT, C_, C_);

    qkv_qk <<<dim3(16, 32), 256, 0, stream>>>(xh, xl, WaTh, WaTl, b_attn,
                                              Qh, Ql, Kh, Kl);
    qkv_v  <<<dim3(8, 32), 256, 0, stream>>>(xh, WaTh + (size_t)2048 * C_,
                                             b_attn + 2048, VT);
    attn_mfma<<<dim3(16, 32), 256, 0, stream>>>(Qh, Ql, Kh, Kl, VT, Yb);
    proj_mfma<<<dim3(8, 32), 256, 0, stream>>>(Yb, WpT, b_proj, out);
}

// Round 11
// 255.779 us; speedup vs baseline: 20.8779x; 1.0373x over previous
//
#include <hip/hip_runtime.h>
#include <hip/hip_bf16.h>

// Problem: CausalSelfAttention  B=2, T=2048, C=1024, H=16, D=64
// Round 11: attn tuning. (1) XCD-aware block swizzle: all 16 q-blocks of a
// (b,h) on one XCD -> K/V stay in that XCD's L2 (3MB/XCD working set).
// (2) Register-prefetch pipeline: next k-tile global loads issued before the
// compute phase, overlapping HBM latency with MFMA. (3) VALU diet: sqrt(D)
// scale folded into Q at qkv epilogue; P->bf16 via truncation.
// S path stays bf16x3 (hh+hl+lh). GEMMs unchanged from r9/r10.
// ws (62 MB): Qh 8|Ql 8|Kh 8|Kl 8|xh 8(->Yb)|xl 8(->VT)|WaTh 6|WaTl 6|WpT 2

#define B_  2
#define T_  2048
#define C_  1024
#define H_  16
#define D_  64
#define M_  (B_ * T_)      // 4096
#define N3_ (3 * C_)       // 3072

typedef __attribute__((ext_vector_type(8))) short s16x8;
typedef __attribute__((ext_vector_type(4))) short s16x4;
typedef __attribute__((ext_vector_type(4))) float f32x4;

typedef const __attribute__((address_space(1))) unsigned int gu32_t;
typedef __attribute__((address_space(3))) unsigned int lu32_t;

__device__ __forceinline__ void gload_lds16(const short* g, short* l) {
    __builtin_amdgcn_global_load_lds((gu32_t*)g, (lu32_t*)l, 16, 0, 0);
}

__device__ __forceinline__ float b2f(unsigned short u) {
    return __uint_as_float(((unsigned)u) << 16);
}
__device__ __forceinline__ unsigned short f2b(float f) {   // RNE bf16 round
    unsigned u = __float_as_uint(f);
    return (unsigned short)((u + 0x7FFFu + ((u >> 16) & 1u)) >> 16);
}

// ---------------------------------------------------------------------------
// fp32 -> (hi, lo) bf16 split. n multiple of 2048.
// ---------------------------------------------------------------------------
__global__ __launch_bounds__(256) void cvt_split(
    const float* __restrict__ in, short* __restrict__ oh, short* __restrict__ ol, int n)
{
    int i = (blockIdx.x * 256 + threadIdx.x) * 8;
    if (i >= n) return;
    float4 a = *(const float4*)&in[i];
    float4 b = *(const float4*)&in[i + 4];
    float v[8] = {a.x, a.y, a.z, a.w, b.x, b.y, b.z, b.w};
    s16x8 h, l;
    #pragma unroll
    for (int j = 0; j < 8; j++) {
        unsigned short hb = f2b(v[j]);
        h[j] = (short)hb;
        l[j] = (short)f2b(v[j] - b2f(hb));
    }
    *(s16x8*)&oh[i] = h;
    *(s16x8*)&ol[i] = l;
}

// ---------------------------------------------------------------------------
// fp32 [R,Cn] -> (hi,lo) bf16 [Cn,R] transpose+split. grid (Cn/64, R/64).
// ---------------------------------------------------------------------------
__global__ __launch_bounds__(256) void cvtT_split(
    const float* __restrict__ in, short* __restrict__ oh, short* __restrict__ ol,
    int R, int Cn)
{
    __shared__ short th[64][80];
    __shared__ short tl[64][80];
    const int tid = threadIdx.x;
    const int k0 = blockIdx.y * 64;
    const int n0 = blockIdx.x * 64;
    {
        int rl = tid >> 4, cl = (tid & 15) * 4;
        #pragma unroll
        for (int i = 0; i < 4; i++) {
            int kr = rl + i * 16;
            float4 v4 = *(const float4*)&in[(size_t)(k0 + kr) * Cn + n0 + cl];
            float v[4] = {v4.x, v4.y, v4.z, v4.w};
            #pragma unroll
            for (int j = 0; j < 4; j++) {
                unsigned short hb = f2b(v[j]);
                th[cl + j][kr] = (short)hb;
                tl[cl + j][kr] = (short)f2b(v[j] - b2f(hb));
            }
        }
    }
    __syncthreads();
    {
        int ro = tid >> 2, co = (tid & 3) * 16;
        *(s16x8*)&oh[(size_t)(n0 + ro) * R + k0 + co]     = *(s16x8*)&th[ro][co];
        *(s16x8*)&oh[(size_t)(n0 + ro) * R + k0 + co + 8] = *(s16x8*)&th[ro][co + 8];
        *(s16x8*)&ol[(size_t)(n0 + ro) * R + k0 + co]     = *(s16x8*)&tl[ro][co];
        *(s16x8*)&ol[(size_t)(n0 + ro) * R + k0 + co + 8] = *(s16x8*)&tl[ro][co + 8];
    }
}

// ---------------------------------------------------------------------------
// fp32 [R,Cn] -> bf16 [Cn,R] transpose (single, for W_proj).
// ---------------------------------------------------------------------------
__global__ __launch_bounds__(256) void cvtT_bf16(
    const float* __restrict__ in, short* __restrict__ out, int R, int Cn)
{
    __shared__ short t[64][80];
    const int tid = threadIdx.x;
    const int k0 = blockIdx.y * 64;
    const int n0 = blockIdx.x * 64;
    {
        int rl = tid >> 4, cl = (tid & 15) * 4;
        #pragma unroll
        for (int i = 0; i < 4; i++) {
            int kr = rl + i * 16;
            float4 v = *(const float4*)&in[(size_t)(k0 + kr) * Cn + n0 + cl];
            t[cl + 0][kr] = (short)f2b(v.x);
            t[cl + 1][kr] = (short)f2b(v.y);
            t[cl + 2][kr] = (short)f2b(v.z);
            t[cl + 3][kr] = (short)f2b(v.w);
        }
    }
    __syncthreads();
    {
        int ro = tid >> 2, co = (tid & 3) * 16;
        *(s16x8*)&out[(size_t)(n0 + ro) * R + k0 + co]     = *(s16x8*)&t[ro][co];
        *(s16x8*)&out[(size_t)(n0 + ro) * R + k0 + co + 8] = *(s16x8*)&t[ro][co + 8];
    }
}

// ---------------------------------------------------------------------------
// qkv_qk: Q,K columns (N=2048), bf16x3, hi/lo scatter. Q pre-scaled by 8
// (sqrt(D), folded out of the attention inner loop).
// ---------------------------------------------------------------------------
__global__ __launch_bounds__(256) void qkv_qk(
    const short* __restrict__ Ah, const short* __restrict__ Al,
    const short* __restrict__ BTh, const short* __restrict__ BTl,
    const float* __restrict__ bias,
    short* __restrict__ Qh, short* __restrict__ Ql,
    short* __restrict__ Kh, short* __restrict__ Kl)
{
    __shared__ short Ash[128 * 32], Asl[128 * 32];
    __shared__ short Bsh[128 * 32], Bsl[128 * 32];

    const int tid  = threadIdx.x;
    const int wave = tid >> 6, lane = tid & 63;
    const int wm = wave >> 1, wn = wave & 1;
    const int lm = lane & 15, lq = lane >> 4;
    const int m0 = blockIdx.y * 128, n0 = blockIdx.x * 128;
    const int gr = (lane >> 2);
    const int gc = (lane & 3) * 8;

    f32x4 acc[4][4] = {};

    for (int k0 = 0; k0 < C_; k0 += 32) {
        __syncthreads();
        #pragma unroll
        for (int j = 0; j < 2; j++) {
            int s = wave * 2 + j;
            int row = s * 16 + gr;
            size_t ga = (size_t)(m0 + row) * C_ + k0 + gc;
            size_t gb = (size_t)(n0 + row) * C_ + k0 + gc;
            gload_lds16(&Ah[ga],  &Ash[s * 512]);
            gload_lds16(&Al[ga],  &Asl[s * 512]);
            gload_lds16(&BTh[gb], &Bsh[s * 512]);
            gload_lds16(&BTl[gb], &Bsl[s * 512]);
        }
        __syncthreads();

        s16x8 ah[4], al[4], bh[4], bl[4];
        #pragma unroll
        for (int mi = 0; mi < 4; mi++) {
            int r = wm * 64 + mi * 16 + lm;
            ah[mi] = *(const s16x8*)&Ash[r * 32 + lq * 8];
            al[mi] = *(const s16x8*)&Asl[r * 32 + lq * 8];
        }
        #pragma unroll
        for (int nj = 0; nj < 4; nj++) {
            int r = wn * 64 + nj * 16 + lm;
            bh[nj] = *(const s16x8*)&Bsh[r * 32 + lq * 8];
            bl[nj] = *(const s16x8*)&Bsl[r * 32 + lq * 8];
        }
        #pragma unroll
        for (int mi = 0; mi < 4; mi++)
            #pragma unroll
            for (int nj = 0; nj < 4; nj++) {
                acc[mi][nj] = __builtin_amdgcn_mfma_f32_16x16x32_bf16(
                    ah[mi], bh[nj], acc[mi][nj], 0, 0, 0);
                acc[mi][nj] = __builtin_amdgcn_mfma_f32_16x16x32_bf16(
                    ah[mi], bl[nj], acc[mi][nj], 0, 0, 0);
                acc[mi][nj] = __builtin_amdgcn_mfma_f32_16x16x32_bf16(
                    al[mi], bh[nj], acc[mi][nj], 0, 0, 0);
            }
    }

    #pragma unroll
    for (int nj = 0; nj < 4; nj++) {
        int n = n0 + wn * 64 + nj * 16 + lm;
        float bv = bias[n];
        int isK = n >> 10;
        int c = n & (C_ - 1);
        int h = c >> 6, d = c & (D_ - 1);
        short* dh = isK ? Kh : Qh;
        short* dl = isK ? Kl : Ql;
        float scale = isK ? 1.0f : 8.0f;     // fold sqrt(D) into Q
        #pragma unroll
        for (int mi = 0; mi < 4; mi++) {
            #pragma unroll
            for (int r = 0; r < 4; r++) {
                int m  = m0 + wm * 64 + mi * 16 + lq * 4 + r;
                int bb = m >> 11, t = m & (T_ - 1);
                float v = (acc[mi][nj][r] + bv) * scale;
                size_t idx = (((size_t)bb * H_ + h) * T_ + t) * D_ + d;
                unsigned short hb = f2b(v);
                dh[idx] = (short)hb;
                dl[idx] = (short)f2b(v - b2f(hb));
            }
        }
    }
}

// ---------------------------------------------------------------------------
// qkv_v: V columns (N=1024), single bf16, scatter TRANSPOSED -> VT [B,H,D,T].
// ---------------------------------------------------------------------------
__global__ __launch_bounds__(256) void qkv_v(
    const short* __restrict__ Ah, const short* __restrict__ BTh,
    const float* __restrict__ bias, short* __restrict__ VT)
{
    __shared__ short Ash[128 * 32];
    __shared__ short Bsh[128 * 32];

    const int tid  = threadIdx.x;
    const int wave = tid >> 6, lane = tid & 63;
    const int wm = wave >> 1, wn = wave & 1;
    const int lm = lane & 15, lq = lane >> 4;
    const int m0 = blockIdx.y * 128, n0 = blockIdx.x * 128;
    const int gr = (lane >> 2);
    const int gc = (lane & 3) * 8;

    f32x4 acc[4][4] = {};

    for (int k0 = 0; k0 < C_; k0 += 32) {
        __syncthreads();
        #pragma unroll
        for (int j = 0; j < 2; j++) {
            int s = wave * 2 + j;
            int row = s * 16 + gr;
            gload_lds16(&Ah[(size_t)(m0 + row) * C_ + k0 + gc],  &Ash[s * 512]);
            gload_lds16(&BTh[(size_t)(n0 + row) * C_ + k0 + gc], &Bsh[s * 512]);
        }
        __syncthreads();

        s16x8 af[4], bfr[4];
        #pragma unroll
        for (int mi = 0; mi < 4; mi++)
            af[mi] = *(const s16x8*)&Ash[(wm * 64 + mi * 16 + lm) * 32 + lq * 8];
        #pragma unroll
        for (int nj = 0; nj < 4; nj++)
            bfr[nj] = *(const s16x8*)&Bsh[(wn * 64 + nj * 16 + lm) * 32 + lq * 8];
        #pragma unroll
        for (int mi = 0; mi < 4; mi++)
            #pragma unroll
            for (int nj = 0; nj < 4; nj++)
                acc[mi][nj] = __builtin_amdgcn_mfma_f32_16x16x32_bf16(
                    af[mi], bfr[nj], acc[mi][nj], 0, 0, 0);
    }

    #pragma unroll
    for (int nj = 0; nj < 4; nj++) {
        int n = n0 + wn * 64 + nj * 16 + lm;    // [0, 1024) V channel
        float bv = bias[n];
        int h = n >> 6, d = n & (D_ - 1);
        #pragma unroll
        for (int mi = 0; mi < 4; mi++) {
            #pragma unroll
            for (int r = 0; r < 4; r++) {
                int m  = m0 + wm * 64 + mi * 16 + lq * 4 + r;
                int bb = m >> 11, t = m & (T_ - 1);
                VT[(((size_t)bb * H_ + h) * D_ + d) * T_ + t] =
                    (short)f2b(acc[mi][nj][r] + bv);
            }
        }
    }
}

// ---------------------------------------------------------------------------
// proj: out fp32 [M,C] = Yb(bf16) @ WpT(bf16) + bias.
// ---------------------------------------------------------------------------
__global__ __launch_bounds__(256) void proj_mfma(
    const short* __restrict__ A, const short* __restrict__ BT,
    const float* __restrict__ bias, float* __restrict__ out)
{
    __shared__ short Ash[128 * 32];
    __shared__ short Bsh[128 * 32];

    const int tid  = threadIdx.x;
    const int wave = tid >> 6, lane = tid & 63;
    const int wm = wave >> 1, wn = wave & 1;
    const int lm = lane & 15, lq = lane >> 4;
    const int m0 = blockIdx.y * 128, n0 = blockIdx.x * 128;
    const int gr = (lane >> 2);
    const int gc = (lane & 3) * 8;

    f32x4 acc[4][4] = {};

    for (int k0 = 0; k0 < C_; k0 += 32) {
        __syncthreads();
        #pragma unroll
        for (int j = 0; j < 2; j++) {
            int s = wave * 2 + j;
            int row = s * 16 + gr;
            gload_lds16(&A[(size_t)(m0 + row) * C_ + k0 + gc],  &Ash[s * 512]);
            gload_lds16(&BT[(size_t)(n0 + row) * C_ + k0 + gc], &Bsh[s * 512]);
        }
        __syncthreads();

        s16x8 af[4], bfr[4];
        #pragma unroll
        for (int mi = 0; mi < 4; mi++)
            af[mi] = *(const s16x8*)&Ash[(wm * 64 + mi * 16 + lm) * 32 + lq * 8];
        #pragma unroll
        for (int nj = 0; nj < 4; nj++)
            bfr[nj] = *(const s16x8*)&Bsh[(wn * 64 + nj * 16 + lm) * 32 + lq * 8];
        #pragma unroll
        for (int mi = 0; mi < 4; mi++)
            #pragma unroll
            for (int nj = 0; nj < 4; nj++)
                acc[mi][nj] = __builtin_amdgcn_mfma_f32_16x16x32_bf16(
                    af[mi], bfr[nj], acc[mi][nj], 0, 0, 0);
    }

    #pragma unroll
    for (int nj = 0; nj < 4; nj++) {
        int n = n0 + wn * 64 + nj * 16 + lm;
        float bv = bias[n];
        #pragma unroll
        for (int mi = 0; mi < 4; mi++) {
            #pragma unroll
            for (int r = 0; r < 4; r++) {
                int m = m0 + wm * 64 + mi * 16 + lq * 4 + r;
                out[(size_t)m * C_ + n] = acc[mi][nj][r] + bv;
            }
        }
    }
}

// ---------------------------------------------------------------------------
// MFMA flash attention, S^T layout, XCD-swizzled 1-D grid, reg-prefetch.
// Q pre-scaled by 8 at qkv. Wave w owns q = q0 + w*16 + lm.
// ---------------------------------------------------------------------------
__global__ __launch_bounds__(256) void attn_mfma(
    const short* __restrict__ Qh, const short* __restrict__ Ql,
    const short* __restrict__ Kh, const short* __restrict__ Kl,
    const short* __restrict__ VT, short* __restrict__ Yb)
{
    __shared__ short Qsh[64][72], Qsl[64][72];   // [q][d]
    __shared__ short Ksh[64][72], Ksl[64][72];   // [key][d]
    __shared__ short Vt [64][72];                // [d][key]
    __shared__ short Ps [4][16][72];             // per-wave P [q][key]

    const int tid  = threadIdx.x;
    const int wave = tid >> 6, lane = tid & 63;
    const int lm   = lane & 15, quad = lane >> 4;

    // XCD swizzle: bid%8 = XCD (heuristic). 4 heads per XCD, 16 q-blocks each.
    const int bid = blockIdx.x;
    const int xcd = bid & 7, s = bid >> 3;
    const int bh  = xcd * 4 + (s >> 4);
    const int qx  = s & 15;
    const int b   = bh >> 4, h = bh & (H_ - 1);
    const size_t base  = (size_t)bh * T_ * D_;   // Q,K: [b,h,t,d]
    const size_t vbase = (size_t)bh * D_ * T_;   // VT:  [b,h,d,t]

    // register prefetch buffers for K hi/lo + Vt staging
    s16x8 pkh[2], pkl[2], pvt[2];
    const int src = tid >> 3;           // staging row 0..31 (+32 for i=1)
    const int sch = (tid & 7) * 8;      // staging col (shorts)

    for (int half = 0; half < 2; half++) {
        const int qt = (half == 0) ? qx : 31 - qx;
        const int q0 = qt * 64;

        __syncthreads();
        #pragma unroll
        for (int i = 0; i < 2; i++) {      // stage Q hi/lo (64 q x 64 d)
            int row = i * 32 + src;
            size_t g = base + (size_t)(q0 + row) * D_ + sch;
            *(s16x8*)&Qsh[row][sch] = *(const s16x8*)&Qh[g];
            *(s16x8*)&Qsl[row][sch] = *(const s16x8*)&Ql[g];
        }
        __syncthreads();

        s16x8 bqh[2], bql[2];
        #pragma unroll
        for (int kc = 0; kc < 2; kc++) {
            bqh[kc] = *(const s16x8*)&Qsh[wave * 16 + lm][kc * 32 + quad * 8];
            bql[kc] = *(const s16x8*)&Qsl[wave * 16 + lm][kc * 32 + quad * 8];
        }

        // prefetch k-tile 0
        #pragma unroll
        for (int i = 0; i < 2; i++) {
            int row = i * 32 + src;
            size_t g = base + (size_t)(row) * D_ + sch;
            pkh[i] = *(const s16x8*)&Kh[g];
            pkl[i] = *(const s16x8*)&Kl[g];
            pvt[i] = *(const s16x8*)&VT[vbase + (size_t)row * T_ + sch];
        }

        float mrow = -INFINITY, lrow = 0.f;
        f32x4 O[4] = {};

        for (int kt = 0; kt <= qt; kt++) {
            __syncthreads();   // prev tile's LDS readers done
            #pragma unroll
            for (int i = 0; i < 2; i++) {  // VGPR -> LDS
                int row = i * 32 + src;
                *(s16x8*)&Ksh[row][sch] = pkh[i];
                *(s16x8*)&Ksl[row][sch] = pkl[i];
                *(s16x8*)&Vt [row][sch] = pvt[i];
            }
            if (kt < qt) {                 // issue next tile's global loads
                #pragma unroll
                for (int i = 0; i < 2; i++) {
                    int row = i * 32 + src;
                    size_t g = base + (size_t)((kt + 1) * 64 + row) * D_ + sch;
                    pkh[i] = *(const s16x8*)&Kh[g];
                    pkl[i] = *(const s16x8*)&Kl[g];
                    pvt[i] = *(const s16x8*)&VT[vbase + (size_t)row * T_ + (kt + 1) * 64 + sch];
                }
            }
            __syncthreads();   // LDS tile ready (loads above still in flight)

            // ---- S^T = K Q^T (bf16x3): A=K (m=key), B=Q (n=q) ----
            f32x4 S[4] = {};
            #pragma unroll
            for (int t = 0; t < 4; t++) {
                #pragma unroll
                for (int kc = 0; kc < 2; kc++) {
                    s16x8 kh8 = *(const s16x8*)&Ksh[t * 16 + lm][kc * 32 + quad * 8];
                    s16x8 kl8 = *(const s16x8*)&Ksl[t * 16 + lm][kc * 32 + quad * 8];
                    S[t] = __builtin_amdgcn_mfma_f32_16x16x32_bf16(kh8, bqh[kc], S[t], 0, 0, 0);
                    S[t] = __builtin_amdgcn_mfma_f32_16x16x32_bf16(kl8, bqh[kc], S[t], 0, 0, 0);
                    S[t] = __builtin_amdgcn_mfma_f32_16x16x32_bf16(kh8, bql[kc], S[t], 0, 0, 0);
                }
            }

            // causal mask only (scale pre-folded into Q)
            const int qg = wave * 16 + lm;
            if (kt == qt) {
                #pragma unroll
                for (int t = 0; t < 4; t++)
                    #pragma unroll
                    for (int r = 0; r < 4; r++)
                        if ((t * 16 + quad * 4 + r) > qg) S[t][r] = -INFINITY;
            }

            // ---- online softmax, one q per thread (replicated x4 quads) ----
            float rm = -INFINITY;
            #pragma unroll
            for (int t = 0; t < 4; t++)
                #pragma unroll
                for (int r = 0; r < 4; r++) rm = fmaxf(rm, S[t][r]);
            rm = fmaxf(rm, __shfl_xor(rm, 16, 64));
            rm = fmaxf(rm, __shfl_xor(rm, 32, 64));
            float mnew  = fmaxf(mrow, rm);
            float alpha = __expf(mrow - mnew);
            mrow = mnew;
            float rs = 0.f;
            #pragma unroll
            for (int t = 0; t < 4; t++)
                #pragma unroll
                for (int r = 0; r < 4; r++) {
                    S[t][r] = __expf(S[t][r] - mnew);
                    rs += S[t][r];
                }
            rs += __shfl_xor(rs, 16, 64);
            rs += __shfl_xor(rs, 32, 64);
            lrow = lrow * alpha + rs;

            float al[4];
            #pragma unroll
            for (int r = 0; r < 4; r++) al[r] = __shfl(alpha, quad * 4 + r, 64);
            #pragma unroll
            for (int t = 0; t < 4; t++)
                #pragma unroll
                for (int r = 0; r < 4; r++) O[t][r] *= al[r];

            // ---- P^T -> Ps[q][key] (truncating bf16; P in [0,1]) ----
            #pragma unroll
            for (int t = 0; t < 4; t++) {
                s16x4 p;
                #pragma unroll
                for (int r = 0; r < 4; r++)
                    p[r] = (short)(__float_as_uint(S[t][r]) >> 16);
                *(s16x4*)&Ps[wave][lm][t * 16 + quad * 4] = p;
            }
            // wave-private slab: no barrier (lgkmcnt ordering within wave)

            // ---- O += P V: A=P (m=q), B=Vt (n=d) ----
            s16x8 ap[2];
            #pragma unroll
            for (int kc = 0; kc < 2; kc++)
                ap[kc] = *(const s16x8*)&Ps[wave][lm][kc * 32 + quad * 8];
            #pragma unroll
            for (int t = 0; t < 4; t++) {
                #pragma unroll
                for (int kc = 0; kc < 2; kc++) {
                    s16x8 bv = *(const s16x8*)&Vt[t * 16 + lm][kc * 32 + quad * 8];
                    O[t] = __builtin_amdgcn_mfma_f32_16x16x32_bf16(ap[kc], bv, O[t], 0, 0, 0);
                }
            }
        }

        // ---- epilogue: O row q = wave*16+quad*4+r, col d = t*16+lm ----
        float li[4];
        #pragma unroll
        for (int r = 0; r < 4; r++)
            li[r] = 1.0f / __shfl(lrow, quad * 4 + r, 64);
        #pragma unroll
        for (int t = 0; t < 4; t++)
            #pragma unroll
            for (int r = 0; r < 4; r++) {
                int q = q0 + wave * 16 + quad * 4 + r;
                int d = t * 16 + lm;
                Yb[((size_t)b * T_ + q) * C_ + h * D_ + d] =
                    (short)f2b(O[t][r] * li[r]);
            }
    }
}

// ---------------------------------------------------------------------------
extern "C" void kernel_launch(void* const* d_in, const int* in_sizes, int n_in,
                              void* d_out, int out_size, void* d_ws, size_t ws_size,
                              hipStream_t stream)
{
    const float* x      = (const float*)d_in[0];
    const float* W_attn = (const float*)d_in[1];
    const float* b_attn = (const float*)d_in[2];
    const float* W_proj = (const float*)d_in[3];
    const float* b_proj = (const float*)d_in[4];
    float* out = (float*)d_out;

    char* ws = (char*)d_ws;
    const size_t MB = 1024 * 1024;
    short* Qh   = (short*)(ws);            // 8 MB  [ 0, 8)
    short* Ql   = (short*)(ws +  8 * MB);  // 8 MB  [ 8,16)
    short* Kh   = (short*)(ws + 16 * MB);  // 8 MB  [16,24)
    short* Kl   = (short*)(ws + 24 * MB);  // 8 MB  [24,32)
    short* xh   = (short*)(ws + 32 * MB);  // 8 MB  [32,40)  dead after qkv_v
    short* xl   = (short*)(ws + 40 * MB);  // 8 MB  [40,48)  dead after qkv_qk
    short* WaTh = (short*)(ws + 48 * MB);  // 6 MB  [48,54)
    short* WaTl = (short*)(ws + 54 * MB);  // 6 MB  [54,60)
    short* WpT  = (short*)(ws + 60 * MB);  // 2 MB  [60,62)
    short* VT   = (short*)(ws + 40 * MB);  // 8 MB  aliases xl (born at qkv_v)
    short* Yb   = (short*)(ws + 32 * MB);  // 8 MB  aliases xh (born at attn)

    cvt_split <<<dim3(M_ * C_ / 2048), 256, 0, stream>>>(x, xh, xl, M_ * C_);
    cvtT_split<<<dim3(N3_ / 64, C_ / 64), 256, 0, stream>>>(W_attn, WaTh, WaTl, C_, N3_);
    cvtT_bf16 <<<dim3(C_ / 64, C_ / 64), 256, 0, stream>>>(W_proj, WpT, C_, C_);

    qkv_qk <<<dim3(16, 32), 256, 0, stream>>>(xh, xl, WaTh, WaTl, b_attn,
                                              Qh, Ql, Kh, Kl);
    qkv_v  <<<dim3(8, 32), 256, 0, stream>>>(xh, WaTh + (size_t)2048 * C_,
                                             b_attn + 2048, VT);
    attn_mfma<<<dim3(512), 256, 0, stream>>>(Qh, Ql, Kh, Kl, VT, Yb);
    proj_mfma<<<dim3(8, 32), 256, 0, stream>>>(Yb, WpT, b_proj, out);
}

// Round 12
// 254.554 us; speedup vs baseline: 20.9783x; 1.0048x over previous
//
#include <hip/hip_runtime.h>
#include <hip/hip_bf16.h>

// Problem: CausalSelfAttention  B=2, T=2048, C=1024, H=16, D=64
// Round 12: attn latency attack. (1) grid 1024: one q-tile/block, balanced
// qt map ({j,15-j,16+j,31-j} per CU-slot class), XCD swizzle kept.
// (2) LDS 55->36KB: Q staged through K buffers (dead after frag hoist) ->
// 4 blocks/CU. (3) exp2 domain: Q pre-scaled by 8*log2(e) at qkv -> softmax
// is native v_exp_f32, no mul. S path stays bf16x3. GEMMs unchanged.
// ws (62 MB): Qh 8|Ql 8|Kh 8|Kl 8|xh 8(->Yb)|xl 8(->VT)|WaTh 6|WaTl 6|WpT 2

#define B_  2
#define T_  2048
#define C_  1024
#define H_  16
#define D_  64
#define M_  (B_ * T_)      // 4096
#define N3_ (3 * C_)       // 3072

typedef __attribute__((ext_vector_type(8))) short s16x8;
typedef __attribute__((ext_vector_type(4))) short s16x4;
typedef __attribute__((ext_vector_type(4))) float f32x4;

typedef const __attribute__((address_space(1))) unsigned int gu32_t;
typedef __attribute__((address_space(3))) unsigned int lu32_t;

__device__ __forceinline__ void gload_lds16(const short* g, short* l) {
    __builtin_amdgcn_global_load_lds((gu32_t*)g, (lu32_t*)l, 16, 0, 0);
}

__device__ __forceinline__ float b2f(unsigned short u) {
    return __uint_as_float(((unsigned)u) << 16);
}
__device__ __forceinline__ unsigned short f2b(float f) {   // RNE bf16 round
    unsigned u = __float_as_uint(f);
    return (unsigned short)((u + 0x7FFFu + ((u >> 16) & 1u)) >> 16);
}
__device__ __forceinline__ float fexp2(float x) {
#if __has_builtin(__builtin_amdgcn_exp2f)
    return __builtin_amdgcn_exp2f(x);
#else
    return exp2f(x);
#endif
}

// ---------------------------------------------------------------------------
// fp32 -> (hi, lo) bf16 split. n multiple of 2048.
// ---------------------------------------------------------------------------
__global__ __launch_bounds__(256) void cvt_split(
    const float* __restrict__ in, short* __restrict__ oh, short* __restrict__ ol, int n)
{
    int i = (blockIdx.x * 256 + threadIdx.x) * 8;
    if (i >= n) return;
    float4 a = *(const float4*)&in[i];
    float4 b = *(const float4*)&in[i + 4];
    float v[8] = {a.x, a.y, a.z, a.w, b.x, b.y, b.z, b.w};
    s16x8 h, l;
    #pragma unroll
    for (int j = 0; j < 8; j++) {
        unsigned short hb = f2b(v[j]);
        h[j] = (short)hb;
        l[j] = (short)f2b(v[j] - b2f(hb));
    }
    *(s16x8*)&oh[i] = h;
    *(s16x8*)&ol[i] = l;
}

// ---------------------------------------------------------------------------
// fp32 [R,Cn] -> (hi,lo) bf16 [Cn,R] transpose+split. grid (Cn/64, R/64).
// ---------------------------------------------------------------------------
__global__ __launch_bounds__(256) void cvtT_split(
    const float* __restrict__ in, short* __restrict__ oh, short* __restrict__ ol,
    int R, int Cn)
{
    __shared__ short th[64][80];
    __shared__ short tl[64][80];
    const int tid = threadIdx.x;
    const int k0 = blockIdx.y * 64;
    const int n0 = blockIdx.x * 64;
    {
        int rl = tid >> 4, cl = (tid & 15) * 4;
        #pragma unroll
        for (int i = 0; i < 4; i++) {
            int kr = rl + i * 16;
            float4 v4 = *(const float4*)&in[(size_t)(k0 + kr) * Cn + n0 + cl];
            float v[4] = {v4.x, v4.y, v4.z, v4.w};
            #pragma unroll
            for (int j = 0; j < 4; j++) {
                unsigned short hb = f2b(v[j]);
                th[cl + j][kr] = (short)hb;
                tl[cl + j][kr] = (short)f2b(v[j] - b2f(hb));
            }
        }
    }
    __syncthreads();
    {
        int ro = tid >> 2, co = (tid & 3) * 16;
        *(s16x8*)&oh[(size_t)(n0 + ro) * R + k0 + co]     = *(s16x8*)&th[ro][co];
        *(s16x8*)&oh[(size_t)(n0 + ro) * R + k0 + co + 8] = *(s16x8*)&th[ro][co + 8];
        *(s16x8*)&ol[(size_t)(n0 + ro) * R + k0 + co]     = *(s16x8*)&tl[ro][co];
        *(s16x8*)&ol[(size_t)(n0 + ro) * R + k0 + co + 8] = *(s16x8*)&tl[ro][co + 8];
    }
}

// ---------------------------------------------------------------------------
// fp32 [R,Cn] -> bf16 [Cn,R] transpose (single, for W_proj).
// ---------------------------------------------------------------------------
__global__ __launch_bounds__(256) void cvtT_bf16(
    const float* __restrict__ in, short* __restrict__ out, int R, int Cn)
{
    __shared__ short t[64][80];
    const int tid = threadIdx.x;
    const int k0 = blockIdx.y * 64;
    const int n0 = blockIdx.x * 64;
    {
        int rl = tid >> 4, cl = (tid & 15) * 4;
        #pragma unroll
        for (int i = 0; i < 4; i++) {
            int kr = rl + i * 16;
            float4 v = *(const float4*)&in[(size_t)(k0 + kr) * Cn + n0 + cl];
            t[cl + 0][kr] = (short)f2b(v.x);
            t[cl + 1][kr] = (short)f2b(v.y);
            t[cl + 2][kr] = (short)f2b(v.z);
            t[cl + 3][kr] = (short)f2b(v.w);
        }
    }
    __syncthreads();
    {
        int ro = tid >> 2, co = (tid & 3) * 16;
        *(s16x8*)&out[(size_t)(n0 + ro) * R + k0 + co]     = *(s16x8*)&t[ro][co];
        *(s16x8*)&out[(size_t)(n0 + ro) * R + k0 + co + 8] = *(s16x8*)&t[ro][co + 8];
    }
}

// ---------------------------------------------------------------------------
// qkv_qk: Q,K columns (N=2048), bf16x3, hi/lo scatter. Q pre-scaled by
// 8*log2(e) (sqrt(D) + exp2-domain fold).
// ---------------------------------------------------------------------------
__global__ __launch_bounds__(256) void qkv_qk(
    const short* __restrict__ Ah, const short* __restrict__ Al,
    const short* __restrict__ BTh, const short* __restrict__ BTl,
    const float* __restrict__ bias,
    short* __restrict__ Qh, short* __restrict__ Ql,
    short* __restrict__ Kh, short* __restrict__ Kl)
{
    __shared__ short Ash[128 * 32], Asl[128 * 32];
    __shared__ short Bsh[128 * 32], Bsl[128 * 32];

    const int tid  = threadIdx.x;
    const int wave = tid >> 6, lane = tid & 63;
    const int wm = wave >> 1, wn = wave & 1;
    const int lm = lane & 15, lq = lane >> 4;
    const int m0 = blockIdx.y * 128, n0 = blockIdx.x * 128;
    const int gr = (lane >> 2);
    const int gc = (lane & 3) * 8;

    f32x4 acc[4][4] = {};

    for (int k0 = 0; k0 < C_; k0 += 32) {
        __syncthreads();
        #pragma unroll
        for (int j = 0; j < 2; j++) {
            int s = wave * 2 + j;
            int row = s * 16 + gr;
            size_t ga = (size_t)(m0 + row) * C_ + k0 + gc;
            size_t gb = (size_t)(n0 + row) * C_ + k0 + gc;
            gload_lds16(&Ah[ga],  &Ash[s * 512]);
            gload_lds16(&Al[ga],  &Asl[s * 512]);
            gload_lds16(&BTh[gb], &Bsh[s * 512]);
            gload_lds16(&BTl[gb], &Bsl[s * 512]);
        }
        __syncthreads();

        s16x8 ah[4], al[4], bh[4], bl[4];
        #pragma unroll
        for (int mi = 0; mi < 4; mi++) {
            int r = wm * 64 + mi * 16 + lm;
            ah[mi] = *(const s16x8*)&Ash[r * 32 + lq * 8];
            al[mi] = *(const s16x8*)&Asl[r * 32 + lq * 8];
        }
        #pragma unroll
        for (int nj = 0; nj < 4; nj++) {
            int r = wn * 64 + nj * 16 + lm;
            bh[nj] = *(const s16x8*)&Bsh[r * 32 + lq * 8];
            bl[nj] = *(const s16x8*)&Bsl[r * 32 + lq * 8];
        }
        #pragma unroll
        for (int mi = 0; mi < 4; mi++)
            #pragma unroll
            for (int nj = 0; nj < 4; nj++) {
                acc[mi][nj] = __builtin_amdgcn_mfma_f32_16x16x32_bf16(
                    ah[mi], bh[nj], acc[mi][nj], 0, 0, 0);
                acc[mi][nj] = __builtin_amdgcn_mfma_f32_16x16x32_bf16(
                    ah[mi], bl[nj], acc[mi][nj], 0, 0, 0);
                acc[mi][nj] = __builtin_amdgcn_mfma_f32_16x16x32_bf16(
                    al[mi], bh[nj], acc[mi][nj], 0, 0, 0);
            }
    }

    #pragma unroll
    for (int nj = 0; nj < 4; nj++) {
        int n = n0 + wn * 64 + nj * 16 + lm;
        float bv = bias[n];
        int isK = n >> 10;
        int c = n & (C_ - 1);
        int h = c >> 6, d = c & (D_ - 1);
        short* dh = isK ? Kh : Qh;
        short* dl = isK ? Kl : Ql;
        // Q carries sqrt(D)=8 and log2(e): softmax runs in exp2 domain
        float scale = isK ? 1.0f : 11.541560327111708f;   // 8*log2(e)
        #pragma unroll
        for (int mi = 0; mi < 4; mi++) {
            #pragma unroll
            for (int r = 0; r < 4; r++) {
                int m  = m0 + wm * 64 + mi * 16 + lq * 4 + r;
                int bb = m >> 11, t = m & (T_ - 1);
                float v = (acc[mi][nj][r] + bv) * scale;
                size_t idx = (((size_t)bb * H_ + h) * T_ + t) * D_ + d;
                unsigned short hb = f2b(v);
                dh[idx] = (short)hb;
                dl[idx] = (short)f2b(v - b2f(hb));
            }
        }
    }
}

// ---------------------------------------------------------------------------
// qkv_v: V columns (N=1024), single bf16, scatter TRANSPOSED -> VT [B,H,D,T].
// ---------------------------------------------------------------------------
__global__ __launch_bounds__(256) void qkv_v(
    const short* __restrict__ Ah, const short* __restrict__ BTh,
    const float* __restrict__ bias, short* __restrict__ VT)
{
    __shared__ short Ash[128 * 32];
    __shared__ short Bsh[128 * 32];

    const int tid  = threadIdx.x;
    const int wave = tid >> 6, lane = tid & 63;
    const int wm = wave >> 1, wn = wave & 1;
    const int lm = lane & 15, lq = lane >> 4;
    const int m0 = blockIdx.y * 128, n0 = blockIdx.x * 128;
    const int gr = (lane >> 2);
    const int gc = (lane & 3) * 8;

    f32x4 acc[4][4] = {};

    for (int k0 = 0; k0 < C_; k0 += 32) {
        __syncthreads();
        #pragma unroll
        for (int j = 0; j < 2; j++) {
            int s = wave * 2 + j;
            int row = s * 16 + gr;
            gload_lds16(&Ah[(size_t)(m0 + row) * C_ + k0 + gc],  &Ash[s * 512]);
            gload_lds16(&BTh[(size_t)(n0 + row) * C_ + k0 + gc], &Bsh[s * 512]);
        }
        __syncthreads();

        s16x8 af[4], bfr[4];
        #pragma unroll
        for (int mi = 0; mi < 4; mi++)
            af[mi] = *(const s16x8*)&Ash[(wm * 64 + mi * 16 + lm) * 32 + lq * 8];
        #pragma unroll
        for (int nj = 0; nj < 4; nj++)
            bfr[nj] = *(const s16x8*)&Bsh[(wn * 64 + nj * 16 + lm) * 32 + lq * 8];
        #pragma unroll
        for (int mi = 0; mi < 4; mi++)
            #pragma unroll
            for (int nj = 0; nj < 4; nj++)
                acc[mi][nj] = __builtin_amdgcn_mfma_f32_16x16x32_bf16(
                    af[mi], bfr[nj], acc[mi][nj], 0, 0, 0);
    }

    #pragma unroll
    for (int nj = 0; nj < 4; nj++) {
        int n = n0 + wn * 64 + nj * 16 + lm;    // [0, 1024) V channel
        float bv = bias[n];
        int h = n >> 6, d = n & (D_ - 1);
        #pragma unroll
        for (int mi = 0; mi < 4; mi++) {
            #pragma unroll
            for (int r = 0; r < 4; r++) {
                int m  = m0 + wm * 64 + mi * 16 + lq * 4 + r;
                int bb = m >> 11, t = m & (T_ - 1);
                VT[(((size_t)bb * H_ + h) * D_ + d) * T_ + t] =
                    (short)f2b(acc[mi][nj][r] + bv);
            }
        }
    }
}

// ---------------------------------------------------------------------------
// proj: out fp32 [M,C] = Yb(bf16) @ WpT(bf16) + bias.
// ---------------------------------------------------------------------------
__global__ __launch_bounds__(256) void proj_mfma(
    const short* __restrict__ A, const short* __restrict__ BT,
    const float* __restrict__ bias, float* __restrict__ out)
{
    __shared__ short Ash[128 * 32];
    __shared__ short Bsh[128 * 32];

    const int tid  = threadIdx.x;
    const int wave = tid >> 6, lane = tid & 63;
    const int wm = wave >> 1, wn = wave & 1;
    const int lm = lane & 15, lq = lane >> 4;
    const int m0 = blockIdx.y * 128, n0 = blockIdx.x * 128;
    const int gr = (lane >> 2);
    const int gc = (lane & 3) * 8;

    f32x4 acc[4][4] = {};

    for (int k0 = 0; k0 < C_; k0 += 32) {
        __syncthreads();
        #pragma unroll
        for (int j = 0; j < 2; j++) {
            int s = wave * 2 + j;
            int row = s * 16 + gr;
            gload_lds16(&A[(size_t)(m0 + row) * C_ + k0 + gc],  &Ash[s * 512]);
            gload_lds16(&BT[(size_t)(n0 + row) * C_ + k0 + gc], &Bsh[s * 512]);
        }
        __syncthreads();

        s16x8 af[4], bfr[4];
        #pragma unroll
        for (int mi = 0; mi < 4; mi++)
            af[mi] = *(const s16x8*)&Ash[(wm * 64 + mi * 16 + lm) * 32 + lq * 8];
        #pragma unroll
        for (int nj = 0; nj < 4; nj++)
            bfr[nj] = *(const s16x8*)&Bsh[(wn * 64 + nj * 16 + lm) * 32 + lq * 8];
        #pragma unroll
        for (int mi = 0; mi < 4; mi++)
            #pragma unroll
            for (int nj = 0; nj < 4; nj++)
                acc[mi][nj] = __builtin_amdgcn_mfma_f32_16x16x32_bf16(
                    af[mi], bfr[nj], acc[mi][nj], 0, 0, 0);
    }

    #pragma unroll
    for (int nj = 0; nj < 4; nj++) {
        int n = n0 + wn * 64 + nj * 16 + lm;
        float bv = bias[n];
        #pragma unroll
        for (int mi = 0; mi < 4; mi++) {
            #pragma unroll
            for (int r = 0; r < 4; r++) {
                int m = m0 + wm * 64 + mi * 16 + lq * 4 + r;
                out[(size_t)m * C_ + n] = acc[mi][nj][r] + bv;
            }
        }
    }
}

// ---------------------------------------------------------------------------
// MFMA flash attention, S^T layout. One q-tile per block, grid 1024.
// bid -> xcd=bid&7 (L2 locality: 4 heads/XCD), balanced qt map so any
// bid-mod-256 class gets qts {j, 15-j, 16+j, 31-j} (sum 62 tiles).
// LDS 36 KB (Q staged through K buffers) -> 4 blocks/CU.
// Q pre-scaled by 8*log2e; softmax in exp2 domain.
// ---------------------------------------------------------------------------
__global__ __launch_bounds__(256) void attn_mfma(
    const short* __restrict__ Qh, const short* __restrict__ Ql,
    const short* __restrict__ Kh, const short* __restrict__ Kl,
    const short* __restrict__ VT, short* __restrict__ Yb)
{
    __shared__ short Ksh[64][72], Ksl[64][72];   // [key][d]; Q staged here 1st
    __shared__ short Vt [64][72];                // [d][key]
    __shared__ short Ps [4][16][72];             // per-wave P [q][key]

    const int tid  = threadIdx.x;
    const int wave = tid >> 6, lane = tid & 63;
    const int lm   = lane & 15, quad = lane >> 4;

    const int bid = blockIdx.x;
    const int xcd = bid & 7;
    const int r_  = bid >> 3;          // 0..127 per XCD
    const int bhl = r_ & 3;
    const int u   = r_ >> 2;           // 0..31
    const int g_  = u >> 3, j_ = u & 7;
    const int qt  = (g_ == 0) ? j_ : (g_ == 1) ? 15 - j_
                  : (g_ == 2) ? 16 + j_ : 31 - j_;
    const int bh  = xcd * 4 + bhl;
    const int b   = bh >> 4, h = bh & (H_ - 1);
    const int q0  = qt * 64;
    const size_t base  = (size_t)bh * T_ * D_;   // Q,K: [b,h,t,d]
    const size_t vbase = (size_t)bh * D_ * T_;   // VT:  [b,h,d,t]

    const int src = tid >> 3;           // staging row 0..31 (+32 for i=1)
    const int sch = (tid & 7) * 8;      // staging col (shorts)

    // ---- stage Q through the K buffers, hoist frags ----
    #pragma unroll
    for (int i = 0; i < 2; i++) {
        int row = i * 32 + src;
        size_t gq = base + (size_t)(q0 + row) * D_ + sch;
        *(s16x8*)&Ksh[row][sch] = *(const s16x8*)&Qh[gq];
        *(s16x8*)&Ksl[row][sch] = *(const s16x8*)&Ql[gq];
    }
    __syncthreads();
    s16x8 bqh[2], bql[2];
    #pragma unroll
    for (int kc = 0; kc < 2; kc++) {
        bqh[kc] = *(const s16x8*)&Ksh[wave * 16 + lm][kc * 32 + quad * 8];
        bql[kc] = *(const s16x8*)&Ksl[wave * 16 + lm][kc * 32 + quad * 8];
    }

    // prefetch k-tile 0 into registers
    s16x8 pkh[2], pkl[2], pvt[2];
    #pragma unroll
    for (int i = 0; i < 2; i++) {
        int row = i * 32 + src;
        size_t gk = base + (size_t)row * D_ + sch;
        pkh[i] = *(const s16x8*)&Kh[gk];
        pkl[i] = *(const s16x8*)&Kl[gk];
        pvt[i] = *(const s16x8*)&VT[vbase + (size_t)row * T_ + sch];
    }

    float mrow = -INFINITY, lrow = 0.f;
    f32x4 O[4] = {};

    for (int kt = 0; kt <= qt; kt++) {
        __syncthreads();   // prev tile's readers (and Q hoist) done
        #pragma unroll
        for (int i = 0; i < 2; i++) {  // VGPR -> LDS
            int row = i * 32 + src;
            *(s16x8*)&Ksh[row][sch] = pkh[i];
            *(s16x8*)&Ksl[row][sch] = pkl[i];
            *(s16x8*)&Vt [row][sch] = pvt[i];
        }
        if (kt < qt) {                 // issue next tile's global loads
            #pragma unroll
            for (int i = 0; i < 2; i++) {
                int row = i * 32 + src;
                size_t gk = base + (size_t)((kt + 1) * 64 + row) * D_ + sch;
                pkh[i] = *(const s16x8*)&Kh[gk];
                pkl[i] = *(const s16x8*)&Kl[gk];
                pvt[i] = *(const s16x8*)&VT[vbase + (size_t)row * T_ + (kt + 1) * 64 + sch];
            }
        }
        __syncthreads();

        // ---- S^T = K Q^T (bf16x3): A=K (m=key), B=Q (n=q) ----
        f32x4 S[4] = {};
        #pragma unroll
        for (int t = 0; t < 4; t++) {
            #pragma unroll
            for (int kc = 0; kc < 2; kc++) {
                s16x8 kh8 = *(const s16x8*)&Ksh[t * 16 + lm][kc * 32 + quad * 8];
                s16x8 kl8 = *(const s16x8*)&Ksl[t * 16 + lm][kc * 32 + quad * 8];
                S[t] = __builtin_amdgcn_mfma_f32_16x16x32_bf16(kh8, bqh[kc], S[t], 0, 0, 0);
                S[t] = __builtin_amdgcn_mfma_f32_16x16x32_bf16(kl8, bqh[kc], S[t], 0, 0, 0);
                S[t] = __builtin_amdgcn_mfma_f32_16x16x32_bf16(kh8, bql[kc], S[t], 0, 0, 0);
            }
        }

        // causal mask (scale pre-folded into Q)
        const int qg = wave * 16 + lm;
        if (kt == qt) {
            #pragma unroll
            for (int t = 0; t < 4; t++)
                #pragma unroll
                for (int r = 0; r < 4; r++)
                    if ((t * 16 + quad * 4 + r) > qg) S[t][r] = -INFINITY;
        }

        // ---- online softmax in exp2 domain, one q per thread ----
        float rm = -INFINITY;
        #pragma unroll
        for (int t = 0; t < 4; t++)
            #pragma unroll
            for (int r = 0; r < 4; r++) rm = fmaxf(rm, S[t][r]);
        rm = fmaxf(rm, __shfl_xor(rm, 16, 64));
        rm = fmaxf(rm, __shfl_xor(rm, 32, 64));
        float mnew  = fmaxf(mrow, rm);
        float alpha = fexp2(mrow - mnew);
        mrow = mnew;
        float rs = 0.f;
        #pragma unroll
        for (int t = 0; t < 4; t++)
            #pragma unroll
            for (int r = 0; r < 4; r++) {
                S[t][r] = fexp2(S[t][r] - mnew);
                rs += S[t][r];
            }
        rs += __shfl_xor(rs, 16, 64);
        rs += __shfl_xor(rs, 32, 64);
        lrow = lrow * alpha + rs;

        float al[4];
        #pragma unroll
        for (int r = 0; r < 4; r++) al[r] = __shfl(alpha, quad * 4 + r, 64);
        #pragma unroll
        for (int t = 0; t < 4; t++)
            #pragma unroll
            for (int r = 0; r < 4; r++) O[t][r] *= al[r];

        // ---- P^T -> Ps[q][key] (truncating bf16; P in [0,1]) ----
        #pragma unroll
        for (int t = 0; t < 4; t++) {
            s16x4 p;
            #pragma unroll
            for (int r = 0; r < 4; r++)
                p[r] = (short)(__float_as_uint(S[t][r]) >> 16);
            *(s16x4*)&Ps[wave][lm][t * 16 + quad * 4] = p;
        }
        // wave-private slab: no barrier (lgkmcnt ordering within wave)

        // ---- O += P V: A=P (m=q), B=Vt (n=d) ----
        s16x8 ap[2];
        #pragma unroll
        for (int kc = 0; kc < 2; kc++)
            ap[kc] = *(const s16x8*)&Ps[wave][lm][kc * 32 + quad * 8];
        #pragma unroll
        for (int t = 0; t < 4; t++) {
            #pragma unroll
            for (int kc = 0; kc < 2; kc++) {
                s16x8 bv = *(const s16x8*)&Vt[t * 16 + lm][kc * 32 + quad * 8];
                O[t] = __builtin_amdgcn_mfma_f32_16x16x32_bf16(ap[kc], bv, O[t], 0, 0, 0);
            }
        }
    }

    // ---- epilogue: O row q = wave*16+quad*4+r, col d = t*16+lm ----
    float li[4];
    #pragma unroll
    for (int r = 0; r < 4; r++)
        li[r] = 1.0f / __shfl(lrow, quad * 4 + r, 64);
    #pragma unroll
    for (int t = 0; t < 4; t++)
        #pragma unroll
        for (int r = 0; r < 4; r++) {
            int q = q0 + wave * 16 + quad * 4 + r;
            int d = t * 16 + lm;
            Yb[((size_t)b * T_ + q) * C_ + h * D_ + d] =
                (short)f2b(O[t][r] * li[r]);
        }
}

// ---------------------------------------------------------------------------
extern "C" void kernel_launch(void* const* d_in, const int* in_sizes, int n_in,
                              void* d_out, int out_size, void* d_ws, size_t ws_size,
                              hipStream_t stream)
{
    const float* x      = (const float*)d_in[0];
    const float* W_attn = (const float*)d_in[1];
    const float* b_attn = (const float*)d_in[2];
    const float* W_proj = (const float*)d_in[3];
    const float* b_proj = (const float*)d_in[4];
    float* out = (float*)d_out;

    char* ws = (char*)d_ws;
    const size_t MB = 1024 * 1024;
    short* Qh   = (short*)(ws);            // 8 MB  [ 0, 8)
    short* Ql   = (short*)(ws +  8 * MB);  // 8 MB  [ 8,16)
    short* Kh   = (short*)(ws + 16 * MB);  // 8 MB  [16,24)
    short* Kl   = (short*)(ws + 24 * MB);  // 8 MB  [24,32)
    short* xh   = (short*)(ws + 32 * MB);  // 8 MB  [32,40)  dead after qkv_v
    short* xl   = (short*)(ws + 40 * MB);  // 8 MB  [40,48)  dead after qkv_qk
    short* WaTh = (short*)(ws + 48 * MB);  // 6 MB  [48,54)
    short* WaTl = (short*)(ws + 54 * MB);  // 6 MB  [54,60)
    short* WpT  = (short*)(ws + 60 * MB);  // 2 MB  [60,62)
    short* VT   = (short*)(ws + 40 * MB);  // 8 MB  aliases xl (born at qkv_v)
    short* Yb   = (short*)(ws + 32 * MB);  // 8 MB  aliases xh (born at attn)

    cvt_split <<<dim3(M_ * C_ / 2048), 256, 0, stream>>>(x, xh, xl, M_ * C_);
    cvtT_split<<<dim3(N3_ / 64, C_ / 64), 256, 0, stream>>>(W_attn, WaTh, WaTl, C_, N3_);
    cvtT_bf16 <<<dim3(C_ / 64, C_ / 64), 256, 0, stream>>>(W_proj, WpT, C_, C_);

    qkv_qk <<<dim3(16, 32), 256, 0, stream>>>(xh, xl, WaTh, WaTl, b_attn,
                                              Qh, Ql, Kh, Kl);
    qkv_v  <<<dim3(8, 32), 256, 0, stream>>>(xh, WaTh + (size_t)2048 * C_,
                                             b_attn + 2048, VT);
    attn_mfma<<<dim3(1024), 256, 0, stream>>>(Qh, Ql, Kh, Kl, VT, Yb);
    proj_mfma<<<dim3(8, 32), 256, 0, stream>>>(Yb, WpT, b_proj, out);
}